// Round 5
// baseline (832.262 us; speedup 1.0000x reference)
//
#include <hip/hip_runtime.h>
#include <math.h>

#define N_NODES 100000
#define N_EDGES 1600000
#define N_GRAPHS 512
#define BN_EPS 1e-5f

#define SCAN_BLOCKS ((N_NODES + 1023) / 1024)   // 98
#define NBUCKET 1024                            // dst>>7 -> 782 used

typedef unsigned int uint;
typedef unsigned short ushort;
typedef unsigned long long u64;
typedef _Float16 f16;
typedef _Float16 f16x8 __attribute__((ext_vector_type(8)));
typedef float f32x4 __attribute__((ext_vector_type(4)));

// ---------------- workspace layout (bytes) ----------------
constexpr size_t OFF_CNT  = 0;          // int[N] in-degree counts            (memset)
constexpr size_t OFF_CUR2 = 400000;     // int[N] pass-2 CSR cursors          (memset)
constexpr size_t OFF_BCNT = 800000;     // int[1024] bucket counts            (memset)
constexpr size_t OFF_BCUR = 804096;     // int[1024] bucket write cursors (init by scan_buckets)
constexpr size_t OFF_ROW  = 808192;     // int[N+1] CSR row starts
constexpr size_t OFF_DIS  = 1208320;    // float[N] rsqrt(deg+1)
constexpr size_t OFF_SC   = 1608320;    // float[64] BN scale
constexpr size_t OFF_SH   = 1608576;    // float[64] BN shift
constexpr size_t OFF_BS   = 1608832;    // int[128] scanned block sums
constexpr size_t OFF_WT   = 1609344;    // f16[128*128 + 64*128] W1^T,W2^T
constexpr size_t OFF_CSR  = 1658496;    // int[E] CSR src indices
constexpr size_t OFF_P    = 8058496;    // 25.6MB: xs(f16) -> h1s(f16) -> h2(f32)
constexpr size_t OFF_Q    = 33658496;   // 25.6MB: binned edges(u64, early) -> M1/M2(f16)

__device__ __forceinline__ uint packf16(float a, float b) {
    union { f16 h[2]; uint u; } z;
    z.h[0] = (f16)a; z.h[1] = (f16)b;
    return z.u;
}
__device__ __forceinline__ float2 unpackf16(uint u) {
    union { uint u; f16 h[2]; } z;
    z.u = u;
    return make_float2((float)z.h[0], (float)z.h[1]);
}

// ---------------- degree count + bucket histogram (one read of dst) ----------------
__global__ __launch_bounds__(256) void count_deg_hist(const int* __restrict__ dst,
                                                      int* __restrict__ cnt,
                                                      int* __restrict__ bcnt) {
    __shared__ int h[NBUCKET];
    for (int i = threadIdx.x; i < NBUCKET; i += 256) h[i] = 0;
    __syncthreads();
    int stride = gridDim.x * 256;
    for (int e = blockIdx.x * 256 + threadIdx.x; e < N_EDGES; e += stride) {
        int d = dst[e];
        atomicAdd(&cnt[d], 1);
        atomicAdd(&h[d >> 7], 1);
    }
    __syncthreads();
    for (int i = threadIdx.x; i < NBUCKET; i += 256) {
        int v = h[i];
        if (v) atomicAdd(&bcnt[i], v);
    }
}

// ---------------- node-count scan (row_start) ----------------
__global__ __launch_bounds__(1024) void scan_block(const int* __restrict__ cnt,
                                                   int* __restrict__ row_start,
                                                   int* __restrict__ block_sums) {
    __shared__ int tmp[1024];
    int t = threadIdx.x;
    int i = blockIdx.x * 1024 + t;
    int v = (i < N_NODES) ? cnt[i] : 0;
    tmp[t] = v;
    __syncthreads();
    for (int off = 1; off < 1024; off <<= 1) {
        int add = (t >= off) ? tmp[t - off] : 0;
        __syncthreads();
        tmp[t] += add;
        __syncthreads();
    }
    if (i < N_NODES) row_start[i] = tmp[t];      // inclusive, block-local
    if (t == 1023) block_sums[blockIdx.x] = tmp[1023];
}

__global__ __launch_bounds__(128) void scan_tops(int* __restrict__ block_sums) {
    __shared__ int tmp[128];
    int t = threadIdx.x;
    tmp[t] = (t < SCAN_BLOCKS) ? block_sums[t] : 0;
    __syncthreads();
    for (int off = 1; off < 128; off <<= 1) {
        int add = (t >= off) ? tmp[t - off] : 0;
        __syncthreads();
        tmp[t] += add;
        __syncthreads();
    }
    block_sums[t] = tmp[t];
}

__global__ __launch_bounds__(1024) void scan_final(const int* __restrict__ cnt,
                                                   const int* __restrict__ block_sums,
                                                   int* __restrict__ row_start,
                                                   float* __restrict__ dis) {
    int t = threadIdx.x;
    int b = blockIdx.x;
    int i = b * 1024 + t;
    if (i < N_NODES) {
        int off = (b == 0) ? 0 : block_sums[b - 1];
        int c = cnt[i];
        row_start[i] = row_start[i] - c + off;   // exclusive
        dis[i] = rsqrtf((float)(c + 1));         // +1 self-loop
    }
    if (i == 0) row_start[N_NODES] = N_EDGES;
}

// ---------------- bucket scan: bcur = exclusive scan of bcnt ----------------
__global__ __launch_bounds__(1024) void scan_buckets(const int* __restrict__ bcnt,
                                                     int* __restrict__ bcur) {
    __shared__ int tmp[NBUCKET];
    int t = threadIdx.x;
    int c = bcnt[t];
    tmp[t] = c;
    __syncthreads();
    for (int off = 1; off < NBUCKET; off <<= 1) {
        int add = (t >= off) ? tmp[t - off] : 0;
        __syncthreads();
        tmp[t] += add;
        __syncthreads();
    }
    bcur[t] = tmp[t] - c;                        // exclusive base; used as cursor
}

// ---------------- pass 1: bin edges by dst>>7 (L2-merged sequential writes per bucket) ----
__global__ __launch_bounds__(256) void bin_scatter(const int* __restrict__ src,
                                                   const int* __restrict__ dst,
                                                   int* __restrict__ bcur,
                                                   u64* __restrict__ binned) {
    int e = blockIdx.x * 256 + threadIdx.x;
    if (e < N_EDGES) {
        int d = dst[e];
        int pos = atomicAdd(&bcur[d >> 7], 1);
        binned[pos] = (u64)(uint)src[e] | ((u64)(uint)d << 32);
    }
}

// ---------------- pass 2: CSR scatter within 128-node windows (localized) ----------------
__global__ __launch_bounds__(256) void csr_from_bins(const u64* __restrict__ binned,
                                                     const int* __restrict__ row_start,
                                                     int* __restrict__ cur2,
                                                     int* __restrict__ csr_src) {
    int e = blockIdx.x * 256 + threadIdx.x;
    if (e < N_EDGES) {
        u64 p = binned[e];
        int s = (int)(uint)(p & 0xffffffffu);
        int d = (int)(uint)(p >> 32);
        int pos = row_start[d] + atomicAdd(&cur2[d], 1);
        csr_src[pos] = s;
    }
}

// ---------------- prep: xs = f16(x * dis[n]), W^T in f16 ----------------
__global__ __launch_bounds__(256) void prep_x(const float* __restrict__ x,
                                              const float* __restrict__ dis,
                                              f16* __restrict__ xs) {
    int i = blockIdx.x * 256 + threadIdx.x;  // over N*32 float4-chunks
    if (i < N_NODES * 32) {
        int n = i >> 5;
        float d = dis[n];
        float4 v = ((const float4*)x)[i];
        uint2 p;
        p.x = packf16(v.x * d, v.y * d);
        p.y = packf16(v.z * d, v.w * d);
        ((uint2*)xs)[i] = p;
    }
}

__global__ __launch_bounds__(256) void prep_w(const float* __restrict__ W1,
                                              const float* __restrict__ W2,
                                              f16* __restrict__ wT) {
    int tid = blockIdx.x * 256 + threadIdx.x;
    if (tid < 16384) {                    // W1^T: wT[n*128+k] = W1[k*128+n]
        int n = tid >> 7, k = tid & 127;
        wT[tid] = (f16)W1[k * 128 + n];
    } else if (tid < 24576) {             // W2^T
        int t = tid - 16384;
        int n = t >> 7, k = t & 127;
        wT[tid] = (f16)W2[k * 64 + n];
    }
}

// ---------------- MFMA GEMM: Y[n,:] = f16( A[n,:] @ B ) ----------------
template <int OUTF>
__global__ __launch_bounds__(256) void gemm_mfma(const f16* __restrict__ A,
                                                 const f16* __restrict__ Bt,
                                                 ushort* __restrict__ Y) {
    constexpr int NT = OUTF / 16;
    constexpr int PITCH = 136;            // +8 f16 pad
    __shared__ f16 sA[64 * PITCH];
    __shared__ f16 sB[OUTF * PITCH];
    int tid = threadIdx.x;
    int n0 = blockIdx.x * 64;

    for (int i = tid; i < 64 * 16; i += 256) {
        int r = i >> 4, c = i & 15;
        int n = n0 + r;
        uint4 v = make_uint4(0, 0, 0, 0);
        if (n < N_NODES) v = ((const uint4*)(A + (size_t)n * 128))[c];
        *(uint4*)&sA[r * PITCH + c * 8] = v;
    }
    for (int i = tid; i < OUTF * 16; i += 256) {
        int r = i >> 4, c = i & 15;
        *(uint4*)&sB[r * PITCH + c * 8] = ((const uint4*)(Bt + r * 128))[c];
    }
    __syncthreads();

    int lane = tid & 63, wave = tid >> 6;
    int l15 = lane & 15, q = lane >> 4;
    int m0 = wave * 16;
    f32x4 acc[NT];
#pragma unroll
    for (int nt = 0; nt < NT; ++nt) acc[nt] = (f32x4){0.f, 0.f, 0.f, 0.f};

    const f16* pa = &sA[(m0 + l15) * PITCH + q * 8];
    const f16* pb = &sB[l15 * PITCH + q * 8];
#pragma unroll
    for (int kk = 0; kk < 4; ++kk) {
        f16x8 a = *(const f16x8*)(pa + kk * 32);
#pragma unroll
        for (int nt = 0; nt < NT; ++nt) {
            f16x8 b = *(const f16x8*)(pb + nt * 16 * PITCH + kk * 32);
            acc[nt] = __builtin_amdgcn_mfma_f32_16x16x32_f16(a, b, acc[nt], 0, 0, 0);
        }
    }

    int row_base = n0 + m0 + q * 4;                     // C/D: col=lane&15, row=q*4+reg
#pragma unroll
    for (int nt = 0; nt < NT; ++nt) {
#pragma unroll
        for (int r = 0; r < 4; ++r) {
            int row = row_base + r;
            if (row < N_NODES) {
                union { f16 h; ushort u; } z;
                z.h = (f16)acc[nt][r];
                Y[(size_t)row * OUTF + nt * 16 + l15] = z.u;
            }
        }
    }
}

// ---- aggregation L1: h1s[d] = f16( relu(dis[d]*sum M1 + b1) * dis[d] ); 4 waves/block, 4x unroll
__global__ __launch_bounds__(256) void aggregate1(const ushort* __restrict__ M,
                                                  const int* __restrict__ row_start,
                                                  const int* __restrict__ csr_src,
                                                  const float* __restrict__ dis,
                                                  const float* __restrict__ bias,
                                                  ushort* __restrict__ H1s) {
    int n = blockIdx.x * 4 + (threadIdx.x >> 6);
    if (n >= N_NODES) return;
    int lane = threadIdx.x & 63;
    float dn = dis[n];
    int e0 = row_start[n], e1 = row_start[n + 1];
    const uint* rows = (const uint*)M;                  // 64 uints (=128 f16) per row
    float2 t0 = unpackf16(rows[(size_t)n * 64 + lane]); // self-loop term
    float a0 = t0.x, a1 = t0.y, b0 = 0.f, b1v = 0.f;
    int e = e0;
    for (; e + 4 <= e1; e += 4) {
        int s0 = csr_src[e], s1 = csr_src[e + 1], s2 = csr_src[e + 2], s3 = csr_src[e + 3];
        uint v0 = rows[(size_t)s0 * 64 + lane];
        uint v1 = rows[(size_t)s1 * 64 + lane];
        uint v2 = rows[(size_t)s2 * 64 + lane];
        uint v3 = rows[(size_t)s3 * 64 + lane];
        float2 f0 = unpackf16(v0), f1 = unpackf16(v1), f2 = unpackf16(v2), f3 = unpackf16(v3);
        a0 += f0.x + f1.x; a1 += f0.y + f1.y;
        b0 += f2.x + f3.x; b1v += f2.y + f3.y;
    }
    for (; e < e1; ++e) {
        float2 f = unpackf16(rows[(size_t)csr_src[e] * 64 + lane]);
        a0 += f.x; a1 += f.y;
    }
    a0 += b0; a1 += b1v;
    a0 = fmaxf(fmaf(a0, dn, bias[2 * lane]), 0.f) * dn;
    a1 = fmaxf(fmaf(a1, dn, bias[2 * lane + 1]), 0.f) * dn;
    ((uint*)H1s)[(size_t)n * 64 + lane] = packf16(a0, a1);
}

// ---- aggregation L2: h2[d] = relu(dis[d]*sum M2 + b2), out f32 ----
__global__ __launch_bounds__(256) void aggregate2(const ushort* __restrict__ M,
                                                  const int* __restrict__ row_start,
                                                  const int* __restrict__ csr_src,
                                                  const float* __restrict__ dis,
                                                  const float* __restrict__ bias,
                                                  float* __restrict__ out) {
    int n = blockIdx.x * 4 + (threadIdx.x >> 6);
    if (n >= N_NODES) return;
    int lane = threadIdx.x & 63;
    float dn = dis[n];
    int e0 = row_start[n], e1 = row_start[n + 1];
    const f16* rows = (const f16*)M;
    float a0 = (float)rows[(size_t)n * 64 + lane];      // self-loop term
    float a1 = 0.f;
    int e = e0;
    for (; e + 4 <= e1; e += 4) {
        int s0 = csr_src[e], s1 = csr_src[e + 1], s2 = csr_src[e + 2], s3 = csr_src[e + 3];
        float v0 = (float)rows[(size_t)s0 * 64 + lane];
        float v1 = (float)rows[(size_t)s1 * 64 + lane];
        float v2 = (float)rows[(size_t)s2 * 64 + lane];
        float v3 = (float)rows[(size_t)s3 * 64 + lane];
        a0 += v0 + v1;
        a1 += v2 + v3;
    }
    for (; e < e1; ++e) a0 += (float)rows[(size_t)csr_src[e] * 64 + lane];
    a0 += a1;
    a0 = fmaf(a0, dn, bias[lane]);
    out[(size_t)n * 64 + lane] = fmaxf(a0, 0.f);
}

// ---------------- pooling ----------------
__global__ __launch_bounds__(64) void pool_graphs(const float* __restrict__ H,
                                                  const int* __restrict__ batch,
                                                  float* __restrict__ pooled) {
    int g = blockIdx.x;
    int lane = threadIdx.x;
    int lo = 0, hi = N_NODES;
    while (lo < hi) { int mid = (lo + hi) >> 1; if (batch[mid] < g) lo = mid + 1; else hi = mid; }
    int start = lo;
    hi = N_NODES;
    while (lo < hi) { int mid = (lo + hi) >> 1; if (batch[mid] < g + 1) lo = mid + 1; else hi = mid; }
    int end = lo;
    float a0 = 0.f, a1 = 0.f;
    int i = start;
    for (; i + 4 <= end; i += 4) {
        a0 += H[(size_t)i * 64 + lane] + H[(size_t)(i + 1) * 64 + lane];
        a1 += H[(size_t)(i + 2) * 64 + lane] + H[(size_t)(i + 3) * 64 + lane];
    }
    for (; i < end; ++i) a0 += H[(size_t)i * 64 + lane];
    pooled[g * 64 + lane] = a0 + a1;
}

// ---------------- BN batch stats -> scale/shift ----------------
__global__ __launch_bounds__(64) void bn_stats(const float* __restrict__ pooled,
                                               const float* __restrict__ gamma,
                                               const float* __restrict__ beta,
                                               float* __restrict__ scale,
                                               float* __restrict__ shift) {
    int f = threadIdx.x;
    float s = 0.f, s2 = 0.f;
    for (int g = 0; g < N_GRAPHS; ++g) {
        float v = pooled[g * 64 + f];
        s += v;
        s2 = fmaf(v, v, s2);
    }
    float mean = s * (1.0f / N_GRAPHS);
    float var = s2 * (1.0f / N_GRAPHS) - mean * mean;
    float istd = rsqrtf(var + BN_EPS);
    float sc = gamma[f] * istd;
    scale[f] = sc;
    shift[f] = beta[f] - mean * sc;
}

// ---------------- head ----------------
__global__ __launch_bounds__(256) void head(const float* __restrict__ pooled,
                                            const float* __restrict__ scale,
                                            const float* __restrict__ shift,
                                            const float* __restrict__ Wo1,
                                            const float* __restrict__ bo1,
                                            const float* __restrict__ Wo2,
                                            const float* __restrict__ bo2,
                                            float* __restrict__ out) {
    __shared__ float sW1[64 * 24];
    __shared__ float sW2[24];
    __shared__ float sb1[24];
    __shared__ float ssc[64];
    __shared__ float ssh[64];
    int tid = threadIdx.x;
    for (int i = tid; i < 64 * 24; i += 256) sW1[i] = Wo1[i];
    if (tid < 24) { sW2[tid] = Wo2[tid]; sb1[tid] = bo1[tid]; }
    if (tid < 64) { ssc[tid] = scale[tid]; ssh[tid] = shift[tid]; }
    __syncthreads();
    int g = blockIdx.x * 256 + tid;
    if (g >= N_GRAPHS) return;
    float xn[64];
    const float* pr = pooled + g * 64;
#pragma unroll
    for (int j = 0; j < 64; ++j) xn[j] = fmaf(pr[j], ssc[j], ssh[j]);
    float o = bo2[0];
#pragma unroll 4
    for (int k = 0; k < 24; ++k) {
        float h = sb1[k];
#pragma unroll
        for (int j = 0; j < 64; ++j) h = fmaf(xn[j], sW1[j * 24 + k], h);
        o = fmaf(fmaxf(h, 0.f), sW2[k], o);
    }
    out[g] = o;
}

extern "C" void kernel_launch(void* const* d_in, const int* in_sizes, int n_in,
                              void* d_out, int out_size, void* d_ws, size_t ws_size,
                              hipStream_t stream) {
    const float* x     = (const float*)d_in[0];
    const int*   ei    = (const int*)d_in[1];   // [2,E]: first E = src, next E = dst
    const int*   batch = (const int*)d_in[2];
    const float* W1    = (const float*)d_in[3];
    const float* b1    = (const float*)d_in[4];
    const float* W2    = (const float*)d_in[5];
    const float* b2    = (const float*)d_in[6];
    const float* gamma = (const float*)d_in[7];
    const float* beta  = (const float*)d_in[8];
    const float* Wo1   = (const float*)d_in[9];
    const float* bo1   = (const float*)d_in[10];
    const float* Wo2   = (const float*)d_in[11];
    const float* bo2   = (const float*)d_in[12];
    float* out = (float*)d_out;               // [512] out, then [512*64] h(=pooled)
    char* ws = (char*)d_ws;

    const int* srcv = ei;
    const int* dstv = ei + N_EDGES;
    int*    cnt      = (int*)(ws + OFF_CNT);
    int*    cur2     = (int*)(ws + OFF_CUR2);
    int*    bcnt     = (int*)(ws + OFF_BCNT);
    int*    bcur     = (int*)(ws + OFF_BCUR);
    int*    row_start= (int*)(ws + OFF_ROW);
    float*  dis      = (float*)(ws + OFF_DIS);
    float*  scale    = (float*)(ws + OFF_SC);
    float*  shift    = (float*)(ws + OFF_SH);
    int*    bsums    = (int*)(ws + OFF_BS);
    f16*    wT       = (f16*)(ws + OFF_WT);
    int*    csr_src  = (int*)(ws + OFF_CSR);
    f16*    bufP     = (f16*)(ws + OFF_P);    // xs -> h1s -> h2(f32)
    ushort* bufQ     = (ushort*)(ws + OFF_Q); // binned(u64, early) -> M1 -> M2
    u64*    binned   = (u64*)(ws + OFF_Q);
    float*  pooled   = out + N_GRAPHS;        // h output region, also used downstream

    // zero cnt + cur2 + bcnt (contiguous)
    hipMemsetAsync(ws + OFF_CNT, 0, 804096, stream);

    int eblocks = (N_EDGES + 255) / 256;
    count_deg_hist<<<256, 256, 0, stream>>>(dstv, cnt, bcnt);
    scan_block<<<SCAN_BLOCKS, 1024, 0, stream>>>(cnt, row_start, bsums);
    scan_tops<<<1, 128, 0, stream>>>(bsums);
    scan_final<<<SCAN_BLOCKS, 1024, 0, stream>>>(cnt, bsums, row_start, dis);
    scan_buckets<<<1, NBUCKET, 0, stream>>>(bcnt, bcur);
    bin_scatter<<<eblocks, 256, 0, stream>>>(srcv, dstv, bcur, binned);
    csr_from_bins<<<eblocks, 256, 0, stream>>>(binned, row_start, cur2, csr_src);

    prep_w<<<96, 256, 0, stream>>>(W1, W2, wT);
    prep_x<<<(N_NODES * 32 + 255) / 256, 256, 0, stream>>>(x, dis, bufP);

    int gblocks = (N_NODES + 63) / 64;
    int ablocks = (N_NODES + 3) / 4;
    gemm_mfma<128><<<gblocks, 256, 0, stream>>>(bufP, wT, bufQ);
    aggregate1<<<ablocks, 256, 0, stream>>>(bufQ, row_start, csr_src, dis, b1, (ushort*)bufP);
    gemm_mfma<64><<<gblocks, 256, 0, stream>>>(bufP, wT + 16384, bufQ);
    aggregate2<<<ablocks, 256, 0, stream>>>(bufQ, row_start, csr_src, dis, b2, (float*)bufP);

    pool_graphs<<<N_GRAPHS, 64, 0, stream>>>((float*)bufP, batch, pooled);
    bn_stats<<<1, 64, 0, stream>>>(pooled, gamma, beta, scale, shift);
    head<<<2, 256, 0, stream>>>(pooled, scale, shift, Wo1, bo1, Wo2, bo2, out);
}

// Round 6
// 442.530 us; speedup vs baseline: 1.8807x; 1.8807x over previous
//
#include <hip/hip_runtime.h>
#include <math.h>

#define N_NODES 100000
#define N_EDGES 1600000
#define N_GRAPHS 512
#define BN_EPS 1e-5f

#define SCAN_BLOCKS ((N_NODES + 1023) / 1024)   // 98
#define NBUCKET 1024                            // dst>>7 -> 782 used
#define NBUCKET_USED ((N_NODES + 127) / 128)    // 782
#define BCHUNK 8192                             // edges per bin_scatter block
#define NCHUNKS ((N_EDGES + BCHUNK - 1) / BCHUNK)  // 196

typedef unsigned int uint;
typedef unsigned short ushort;
typedef unsigned long long u64;
typedef _Float16 f16;
typedef _Float16 f16x8 __attribute__((ext_vector_type(8)));
typedef float f32x4 __attribute__((ext_vector_type(4)));

// ---------------- workspace layout (bytes) ----------------
constexpr size_t OFF_CNT  = 0;          // int[N] in-degree counts            (memset)
constexpr size_t OFF_BCNT = 400000;     // int[1024] bucket counts            (memset)
constexpr size_t OFF_BCUR = 404096;     // int[1024] bucket cursors (init by scan_buckets)
constexpr size_t OFF_ROW  = 408192;     // int[N+1] CSR row starts
constexpr size_t OFF_DIS  = 808320;     // float[N] rsqrt(deg+1)
constexpr size_t OFF_SC   = 1208320;    // float[64] BN scale
constexpr size_t OFF_SH   = 1208576;    // float[64] BN shift
constexpr size_t OFF_BS   = 1208832;    // int[128] scanned block sums
constexpr size_t OFF_WT   = 1209344;    // f16[128*128 + 64*128] W1^T,W2^T
constexpr size_t OFF_CSR  = 1258496;    // int[E] CSR src indices
constexpr size_t OFF_P    = 7658496;    // 25.6MB: xs(f16) -> h1s(f16) -> h2(f32)
constexpr size_t OFF_Q    = 33258496;   // 25.6MB: binned edges(u64, early) -> M1/M2(f16)

__device__ __forceinline__ uint packf16(float a, float b) {
    union { f16 h[2]; uint u; } z;
    z.h[0] = (f16)a; z.h[1] = (f16)b;
    return z.u;
}
__device__ __forceinline__ float2 unpackf16(uint u) {
    union { uint u; f16 h[2]; } z;
    z.u = u;
    return make_float2((float)z.h[0], (float)z.h[1]);
}

// ---------------- degree count + bucket histogram (one read of dst) ----------------
__global__ __launch_bounds__(256) void count_deg_hist(const int* __restrict__ dst,
                                                      int* __restrict__ cnt,
                                                      int* __restrict__ bcnt) {
    __shared__ int h[NBUCKET];
    for (int i = threadIdx.x; i < NBUCKET; i += 256) h[i] = 0;
    __syncthreads();
    int stride = gridDim.x * 256;
    for (int e = blockIdx.x * 256 + threadIdx.x; e < N_EDGES; e += stride) {
        int d = dst[e];
        atomicAdd(&cnt[d], 1);          // 100k counters: low contention
        atomicAdd(&h[d >> 7], 1);       // LDS
    }
    __syncthreads();
    for (int i = threadIdx.x; i < NBUCKET; i += 256) {
        int v = h[i];
        if (v) atomicAdd(&bcnt[i], v);  // 256 blocks x <=782: block-level only
    }
}

// ---------------- node-count scan (row_start) ----------------
__global__ __launch_bounds__(1024) void scan_block(const int* __restrict__ cnt,
                                                   int* __restrict__ row_start,
                                                   int* __restrict__ block_sums) {
    __shared__ int tmp[1024];
    int t = threadIdx.x;
    int i = blockIdx.x * 1024 + t;
    int v = (i < N_NODES) ? cnt[i] : 0;
    tmp[t] = v;
    __syncthreads();
    for (int off = 1; off < 1024; off <<= 1) {
        int add = (t >= off) ? tmp[t - off] : 0;
        __syncthreads();
        tmp[t] += add;
        __syncthreads();
    }
    if (i < N_NODES) row_start[i] = tmp[t];      // inclusive, block-local
    if (t == 1023) block_sums[blockIdx.x] = tmp[1023];
}

__global__ __launch_bounds__(128) void scan_tops(int* __restrict__ block_sums) {
    __shared__ int tmp[128];
    int t = threadIdx.x;
    tmp[t] = (t < SCAN_BLOCKS) ? block_sums[t] : 0;
    __syncthreads();
    for (int off = 1; off < 128; off <<= 1) {
        int add = (t >= off) ? tmp[t - off] : 0;
        __syncthreads();
        tmp[t] += add;
        __syncthreads();
    }
    block_sums[t] = tmp[t];
}

__global__ __launch_bounds__(1024) void scan_final(const int* __restrict__ cnt,
                                                   const int* __restrict__ block_sums,
                                                   int* __restrict__ row_start,
                                                   float* __restrict__ dis) {
    int t = threadIdx.x;
    int b = blockIdx.x;
    int i = b * 1024 + t;
    if (i < N_NODES) {
        int off = (b == 0) ? 0 : block_sums[b - 1];
        int c = cnt[i];
        row_start[i] = row_start[i] - c + off;   // exclusive
        dis[i] = rsqrtf((float)(c + 1));         // +1 self-loop
    }
    if (i == 0) row_start[N_NODES] = N_EDGES;
}

// ---------------- bucket scan: bcur = exclusive scan of bcnt ----------------
__global__ __launch_bounds__(1024) void scan_buckets(const int* __restrict__ bcnt,
                                                     int* __restrict__ bcur) {
    __shared__ int tmp[NBUCKET];
    int t = threadIdx.x;
    int c = bcnt[t];
    tmp[t] = c;
    __syncthreads();
    for (int off = 1; off < NBUCKET; off <<= 1) {
        int add = (t >= off) ? tmp[t - off] : 0;
        __syncthreads();
        tmp[t] += add;
        __syncthreads();
    }
    bcur[t] = tmp[t] - c;                        // exclusive base; consumed as cursor
}

// ---- pass 1: bin edges by dst>>7. Per-edge atomics in LDS only; one global
// ---- atomicAdd per (block,bucket) reserves a contiguous run. ----
__global__ __launch_bounds__(1024) void bin_scatter(const int* __restrict__ src,
                                                    const int* __restrict__ dst,
                                                    int* __restrict__ bcur,
                                                    u64* __restrict__ binned) {
    constexpr int REG = BCHUNK / 1024;           // 8 edges per thread
    __shared__ int hist[NBUCKET];                // pass A: counts; pass B: local cursors
    __shared__ int base[NBUCKET];                // global run base for this block
    int t = threadIdx.x;
    int e0 = blockIdx.x * BCHUNK;
    int lim = N_EDGES - e0;                      // edges in this chunk (may exceed BCHUNK)

    hist[t] = 0;
    __syncthreads();

    int ds[REG], ss[REG];
#pragma unroll
    for (int i = 0; i < REG; ++i) {
        int idx = t + i * 1024;
        if (idx < lim) {
            ds[i] = dst[e0 + idx];
            ss[i] = src[e0 + idx];
            atomicAdd(&hist[ds[i] >> 7], 1);
        }
    }
    __syncthreads();

    int h = hist[t];
    base[t] = h ? atomicAdd(&bcur[t], h) : 0;    // block-level reservation
    hist[t] = 0;                                 // reuse as local cursor
    __syncthreads();

#pragma unroll
    for (int i = 0; i < REG; ++i) {
        int idx = t + i * 1024;
        if (idx < lim) {
            int b = ds[i] >> 7;
            int pos = base[b] + atomicAdd(&hist[b], 1);
            binned[pos] = (u64)(uint)ss[i] | ((u64)(uint)ds[i] << 32);
        }
    }
}

// ---- pass 2: one block per bucket; CSR placement with 128 LDS cursors.
// ---- All writes confined to this bucket's CSR window, from one CU. ----
__global__ __launch_bounds__(256) void csr_from_bins(const u64* __restrict__ binned,
                                                     const int* __restrict__ bcur,
                                                     const int* __restrict__ row_start,
                                                     int* __restrict__ csr_src) {
    __shared__ int cur[128];
    int t = threadIdx.x;
    int b = blockIdx.x;
    if (t < 128) cur[t] = 0;
    __syncthreads();
    int start = (b == 0) ? 0 : bcur[b - 1];      // bcur is inclusive scan after bin_scatter
    int end = bcur[b];
    for (int i = start + t; i < end; i += 256) {
        u64 p = binned[i];
        int s = (int)(uint)(p & 0xffffffffu);
        int d = (int)(uint)(p >> 32);
        int pos = row_start[d] + atomicAdd(&cur[d & 127], 1);
        csr_src[pos] = s;
    }
}

// ---------------- prep: xs = f16(x * dis[n]), W^T in f16 ----------------
__global__ __launch_bounds__(256) void prep_x(const float* __restrict__ x,
                                              const float* __restrict__ dis,
                                              f16* __restrict__ xs) {
    int i = blockIdx.x * 256 + threadIdx.x;  // over N*32 float4-chunks
    if (i < N_NODES * 32) {
        int n = i >> 5;
        float d = dis[n];
        float4 v = ((const float4*)x)[i];
        uint2 p;
        p.x = packf16(v.x * d, v.y * d);
        p.y = packf16(v.z * d, v.w * d);
        ((uint2*)xs)[i] = p;
    }
}

__global__ __launch_bounds__(256) void prep_w(const float* __restrict__ W1,
                                              const float* __restrict__ W2,
                                              f16* __restrict__ wT) {
    int tid = blockIdx.x * 256 + threadIdx.x;
    if (tid < 16384) {                    // W1^T: wT[n*128+k] = W1[k*128+n]
        int n = tid >> 7, k = tid & 127;
        wT[tid] = (f16)W1[k * 128 + n];
    } else if (tid < 24576) {             // W2^T
        int t = tid - 16384;
        int n = t >> 7, k = t & 127;
        wT[tid] = (f16)W2[k * 64 + n];
    }
}

// ---------------- MFMA GEMM: Y[n,:] = f16( A[n,:] @ B ) ----------------
template <int OUTF>
__global__ __launch_bounds__(256) void gemm_mfma(const f16* __restrict__ A,
                                                 const f16* __restrict__ Bt,
                                                 ushort* __restrict__ Y) {
    constexpr int NT = OUTF / 16;
    constexpr int PITCH = 136;            // +8 f16 pad
    __shared__ f16 sA[64 * PITCH];
    __shared__ f16 sB[OUTF * PITCH];
    int tid = threadIdx.x;
    int n0 = blockIdx.x * 64;

    for (int i = tid; i < 64 * 16; i += 256) {
        int r = i >> 4, c = i & 15;
        int n = n0 + r;
        uint4 v = make_uint4(0, 0, 0, 0);
        if (n < N_NODES) v = ((const uint4*)(A + (size_t)n * 128))[c];
        *(uint4*)&sA[r * PITCH + c * 8] = v;
    }
    for (int i = tid; i < OUTF * 16; i += 256) {
        int r = i >> 4, c = i & 15;
        *(uint4*)&sB[r * PITCH + c * 8] = ((const uint4*)(Bt + r * 128))[c];
    }
    __syncthreads();

    int lane = tid & 63, wave = tid >> 6;
    int l15 = lane & 15, q = lane >> 4;
    int m0 = wave * 16;
    f32x4 acc[NT];
#pragma unroll
    for (int nt = 0; nt < NT; ++nt) acc[nt] = (f32x4){0.f, 0.f, 0.f, 0.f};

    const f16* pa = &sA[(m0 + l15) * PITCH + q * 8];
    const f16* pb = &sB[l15 * PITCH + q * 8];
#pragma unroll
    for (int kk = 0; kk < 4; ++kk) {
        f16x8 a = *(const f16x8*)(pa + kk * 32);
#pragma unroll
        for (int nt = 0; nt < NT; ++nt) {
            f16x8 b = *(const f16x8*)(pb + nt * 16 * PITCH + kk * 32);
            acc[nt] = __builtin_amdgcn_mfma_f32_16x16x32_f16(a, b, acc[nt], 0, 0, 0);
        }
    }

    int row_base = n0 + m0 + q * 4;                     // C/D: col=lane&15, row=q*4+reg
#pragma unroll
    for (int nt = 0; nt < NT; ++nt) {
#pragma unroll
        for (int r = 0; r < 4; ++r) {
            int row = row_base + r;
            if (row < N_NODES) {
                union { f16 h; ushort u; } z;
                z.h = (f16)acc[nt][r];
                Y[(size_t)row * OUTF + nt * 16 + l15] = z.u;
            }
        }
    }
}

// ---- aggregation L1: h1s[d] = f16( relu(dis[d]*sum M1 + b1) * dis[d] ); 4 waves/block, 4x unroll
__global__ __launch_bounds__(256) void aggregate1(const ushort* __restrict__ M,
                                                  const int* __restrict__ row_start,
                                                  const int* __restrict__ csr_src,
                                                  const float* __restrict__ dis,
                                                  const float* __restrict__ bias,
                                                  ushort* __restrict__ H1s) {
    int n = blockIdx.x * 4 + (threadIdx.x >> 6);
    if (n >= N_NODES) return;
    int lane = threadIdx.x & 63;
    float dn = dis[n];
    int e0 = row_start[n], e1 = row_start[n + 1];
    const uint* rows = (const uint*)M;                  // 64 uints (=128 f16) per row
    float2 t0 = unpackf16(rows[(size_t)n * 64 + lane]); // self-loop term
    float a0 = t0.x, a1 = t0.y, b0 = 0.f, b1v = 0.f;
    int e = e0;
    for (; e + 4 <= e1; e += 4) {
        int s0 = csr_src[e], s1 = csr_src[e + 1], s2 = csr_src[e + 2], s3 = csr_src[e + 3];
        uint v0 = rows[(size_t)s0 * 64 + lane];
        uint v1 = rows[(size_t)s1 * 64 + lane];
        uint v2 = rows[(size_t)s2 * 64 + lane];
        uint v3 = rows[(size_t)s3 * 64 + lane];
        float2 f0 = unpackf16(v0), f1 = unpackf16(v1), f2 = unpackf16(v2), f3 = unpackf16(v3);
        a0 += f0.x + f1.x; a1 += f0.y + f1.y;
        b0 += f2.x + f3.x; b1v += f2.y + f3.y;
    }
    for (; e < e1; ++e) {
        float2 f = unpackf16(rows[(size_t)csr_src[e] * 64 + lane]);
        a0 += f.x; a1 += f.y;
    }
    a0 += b0; a1 += b1v;
    a0 = fmaxf(fmaf(a0, dn, bias[2 * lane]), 0.f) * dn;
    a1 = fmaxf(fmaf(a1, dn, bias[2 * lane + 1]), 0.f) * dn;
    ((uint*)H1s)[(size_t)n * 64 + lane] = packf16(a0, a1);
}

// ---- aggregation L2: h2[d] = relu(dis[d]*sum M2 + b2), out f32 ----
__global__ __launch_bounds__(256) void aggregate2(const ushort* __restrict__ M,
                                                  const int* __restrict__ row_start,
                                                  const int* __restrict__ csr_src,
                                                  const float* __restrict__ dis,
                                                  const float* __restrict__ bias,
                                                  float* __restrict__ out) {
    int n = blockIdx.x * 4 + (threadIdx.x >> 6);
    if (n >= N_NODES) return;
    int lane = threadIdx.x & 63;
    float dn = dis[n];
    int e0 = row_start[n], e1 = row_start[n + 1];
    const f16* rows = (const f16*)M;
    float a0 = (float)rows[(size_t)n * 64 + lane];      // self-loop term
    float a1 = 0.f;
    int e = e0;
    for (; e + 4 <= e1; e += 4) {
        int s0 = csr_src[e], s1 = csr_src[e + 1], s2 = csr_src[e + 2], s3 = csr_src[e + 3];
        float v0 = (float)rows[(size_t)s0 * 64 + lane];
        float v1 = (float)rows[(size_t)s1 * 64 + lane];
        float v2 = (float)rows[(size_t)s2 * 64 + lane];
        float v3 = (float)rows[(size_t)s3 * 64 + lane];
        a0 += v0 + v1;
        a1 += v2 + v3;
    }
    for (; e < e1; ++e) a0 += (float)rows[(size_t)csr_src[e] * 64 + lane];
    a0 += a1;
    a0 = fmaf(a0, dn, bias[lane]);
    out[(size_t)n * 64 + lane] = fmaxf(a0, 0.f);
}

// ---------------- pooling ----------------
__global__ __launch_bounds__(64) void pool_graphs(const float* __restrict__ H,
                                                  const int* __restrict__ batch,
                                                  float* __restrict__ pooled) {
    int g = blockIdx.x;
    int lane = threadIdx.x;
    int lo = 0, hi = N_NODES;
    while (lo < hi) { int mid = (lo + hi) >> 1; if (batch[mid] < g) lo = mid + 1; else hi = mid; }
    int start = lo;
    hi = N_NODES;
    while (lo < hi) { int mid = (lo + hi) >> 1; if (batch[mid] < g + 1) lo = mid + 1; else hi = mid; }
    int end = lo;
    float a0 = 0.f, a1 = 0.f;
    int i = start;
    for (; i + 4 <= end; i += 4) {
        a0 += H[(size_t)i * 64 + lane] + H[(size_t)(i + 1) * 64 + lane];
        a1 += H[(size_t)(i + 2) * 64 + lane] + H[(size_t)(i + 3) * 64 + lane];
    }
    for (; i < end; ++i) a0 += H[(size_t)i * 64 + lane];
    pooled[g * 64 + lane] = a0 + a1;
}

// ---------------- BN batch stats -> scale/shift ----------------
__global__ __launch_bounds__(64) void bn_stats(const float* __restrict__ pooled,
                                               const float* __restrict__ gamma,
                                               const float* __restrict__ beta,
                                               float* __restrict__ scale,
                                               float* __restrict__ shift) {
    int f = threadIdx.x;
    float s = 0.f, s2 = 0.f;
    for (int g = 0; g < N_GRAPHS; ++g) {
        float v = pooled[g * 64 + f];
        s += v;
        s2 = fmaf(v, v, s2);
    }
    float mean = s * (1.0f / N_GRAPHS);
    float var = s2 * (1.0f / N_GRAPHS) - mean * mean;
    float istd = rsqrtf(var + BN_EPS);
    float sc = gamma[f] * istd;
    scale[f] = sc;
    shift[f] = beta[f] - mean * sc;
}

// ---------------- head ----------------
__global__ __launch_bounds__(256) void head(const float* __restrict__ pooled,
                                            const float* __restrict__ scale,
                                            const float* __restrict__ shift,
                                            const float* __restrict__ Wo1,
                                            const float* __restrict__ bo1,
                                            const float* __restrict__ Wo2,
                                            const float* __restrict__ bo2,
                                            float* __restrict__ out) {
    __shared__ float sW1[64 * 24];
    __shared__ float sW2[24];
    __shared__ float sb1[24];
    __shared__ float ssc[64];
    __shared__ float ssh[64];
    int tid = threadIdx.x;
    for (int i = tid; i < 64 * 24; i += 256) sW1[i] = Wo1[i];
    if (tid < 24) { sW2[tid] = Wo2[tid]; sb1[tid] = bo1[tid]; }
    if (tid < 64) { ssc[tid] = scale[tid]; ssh[tid] = shift[tid]; }
    __syncthreads();
    int g = blockIdx.x * 256 + tid;
    if (g >= N_GRAPHS) return;
    float xn[64];
    const float* pr = pooled + g * 64;
#pragma unroll
    for (int j = 0; j < 64; ++j) xn[j] = fmaf(pr[j], ssc[j], ssh[j]);
    float o = bo2[0];
#pragma unroll 4
    for (int k = 0; k < 24; ++k) {
        float h = sb1[k];
#pragma unroll
        for (int j = 0; j < 64; ++j) h = fmaf(xn[j], sW1[j * 24 + k], h);
        o = fmaf(fmaxf(h, 0.f), sW2[k], o);
    }
    out[g] = o;
}

extern "C" void kernel_launch(void* const* d_in, const int* in_sizes, int n_in,
                              void* d_out, int out_size, void* d_ws, size_t ws_size,
                              hipStream_t stream) {
    const float* x     = (const float*)d_in[0];
    const int*   ei    = (const int*)d_in[1];   // [2,E]: first E = src, next E = dst
    const int*   batch = (const int*)d_in[2];
    const float* W1    = (const float*)d_in[3];
    const float* b1    = (const float*)d_in[4];
    const float* W2    = (const float*)d_in[5];
    const float* b2    = (const float*)d_in[6];
    const float* gamma = (const float*)d_in[7];
    const float* beta  = (const float*)d_in[8];
    const float* Wo1   = (const float*)d_in[9];
    const float* bo1   = (const float*)d_in[10];
    const float* Wo2   = (const float*)d_in[11];
    const float* bo2   = (const float*)d_in[12];
    float* out = (float*)d_out;               // [512] out, then [512*64] h(=pooled)
    char* ws = (char*)d_ws;

    const int* srcv = ei;
    const int* dstv = ei + N_EDGES;
    int*    cnt      = (int*)(ws + OFF_CNT);
    int*    bcnt     = (int*)(ws + OFF_BCNT);
    int*    bcur     = (int*)(ws + OFF_BCUR);
    int*    row_start= (int*)(ws + OFF_ROW);
    float*  dis      = (float*)(ws + OFF_DIS);
    float*  scale    = (float*)(ws + OFF_SC);
    float*  shift    = (float*)(ws + OFF_SH);
    int*    bsums    = (int*)(ws + OFF_BS);
    f16*    wT       = (f16*)(ws + OFF_WT);
    int*    csr_src  = (int*)(ws + OFF_CSR);
    f16*    bufP     = (f16*)(ws + OFF_P);    // xs -> h1s -> h2(f32)
    ushort* bufQ     = (ushort*)(ws + OFF_Q); // binned(u64, early) -> M1 -> M2
    u64*    binned   = (u64*)(ws + OFF_Q);
    float*  pooled   = out + N_GRAPHS;        // h output region, also used downstream

    // zero cnt + bcnt (contiguous)
    hipMemsetAsync(ws + OFF_CNT, 0, 404096, stream);

    count_deg_hist<<<256, 256, 0, stream>>>(dstv, cnt, bcnt);
    scan_block<<<SCAN_BLOCKS, 1024, 0, stream>>>(cnt, row_start, bsums);
    scan_tops<<<1, 128, 0, stream>>>(bsums);
    scan_final<<<SCAN_BLOCKS, 1024, 0, stream>>>(cnt, bsums, row_start, dis);
    scan_buckets<<<1, NBUCKET, 0, stream>>>(bcnt, bcur);
    bin_scatter<<<NCHUNKS, 1024, 0, stream>>>(srcv, dstv, bcur, binned);
    csr_from_bins<<<NBUCKET_USED, 256, 0, stream>>>(binned, bcur, row_start, csr_src);

    prep_w<<<96, 256, 0, stream>>>(W1, W2, wT);
    prep_x<<<(N_NODES * 32 + 255) / 256, 256, 0, stream>>>(x, dis, bufP);

    int gblocks = (N_NODES + 63) / 64;
    int ablocks = (N_NODES + 3) / 4;
    gemm_mfma<128><<<gblocks, 256, 0, stream>>>(bufP, wT, bufQ);
    aggregate1<<<ablocks, 256, 0, stream>>>(bufQ, row_start, csr_src, dis, b1, (ushort*)bufP);
    gemm_mfma<64><<<gblocks, 256, 0, stream>>>(bufP, wT + 16384, bufQ);
    aggregate2<<<ablocks, 256, 0, stream>>>(bufQ, row_start, csr_src, dis, b2, (float*)bufP);

    pool_graphs<<<N_GRAPHS, 64, 0, stream>>>((float*)bufP, batch, pooled);
    bn_stats<<<1, 64, 0, stream>>>(pooled, gamma, beta, scale, shift);
    head<<<2, 256, 0, stream>>>(pooled, scale, shift, Wo1, bo1, Wo2, bo2, out);
}

// Round 7
// 368.654 us; speedup vs baseline: 2.2576x; 1.2004x over previous
//
#include <hip/hip_runtime.h>
#include <math.h>

#define N_NODES 100000
#define N_EDGES 1600000
#define N_GRAPHS 512
#define BN_EPS 1e-5f

#define NBUCKET 1024                            // dst>>7 -> 782 used
#define NBUCKET_USED ((N_NODES + 127) / 128)    // 782
#define BCHUNK 8192                             // edges per bin_scatter block
#define NCHUNKS ((N_EDGES + BCHUNK - 1) / BCHUNK)  // 196

typedef unsigned int uint;
typedef unsigned short ushort;
typedef unsigned long long u64;
typedef _Float16 f16;
typedef _Float16 f16x8 __attribute__((ext_vector_type(8)));
typedef float f32x4 __attribute__((ext_vector_type(4)));

// ---------------- workspace layout (bytes) ----------------
constexpr size_t OFF_BCNT  = 0;          // int[1024] bucket counts        (memset)
constexpr size_t OFF_BCUR  = 4096;       // int[1024] bucket cursors
constexpr size_t OFF_BBASE = 8192;       // int[1024] bucket exclusive bases
constexpr size_t OFF_DIS   = 12288;      // float[N] rsqrt(deg+1)
constexpr size_t OFF_ROW   = 412288;     // int[N+1] CSR row starts
constexpr size_t OFF_SC    = 812416;     // float[64] BN scale
constexpr size_t OFF_SH    = 812672;     // float[64] BN shift
constexpr size_t OFF_WT    = 812928;     // f16[128*128 + 64*128] W1^T,W2^T
constexpr size_t OFF_CSR   = 862080;     // int[E] CSR src indices
constexpr size_t OFF_P     = 7262080;    // 25.6MB: h1s(f16) -> h2(f32)
constexpr size_t OFF_Q     = 32862080;   // 25.6MB: binned(u64, early) -> M1/M2(f16)

__device__ __forceinline__ uint packf16(float a, float b) {
    union { f16 h[2]; uint u; } z;
    z.h[0] = (f16)a; z.h[1] = (f16)b;
    return z.u;
}
__device__ __forceinline__ float2 unpackf16(uint u) {
    union { uint u; f16 h[2]; } z;
    z.u = u;
    return make_float2((float)z.h[0], (float)z.h[1]);
}

// ---------------- bucket histogram (LDS only; no per-node atomics) ----------------
__global__ __launch_bounds__(256) void bucket_hist(const int* __restrict__ dst,
                                                   int* __restrict__ bcnt) {
    __shared__ int h[NBUCKET];
    for (int i = threadIdx.x; i < NBUCKET; i += 256) h[i] = 0;
    __syncthreads();
    int stride = gridDim.x * 256;
    for (int e = blockIdx.x * 256 + threadIdx.x; e < N_EDGES; e += stride)
        atomicAdd(&h[dst[e] >> 7], 1);
    __syncthreads();
    for (int i = threadIdx.x; i < NBUCKET; i += 256) {
        int v = h[i];
        if (v) atomicAdd(&bcnt[i], v);
    }
}

// ---------------- bucket scan -> exclusive bases (bcur = working cursor copy) ----------------
__global__ __launch_bounds__(1024) void scan_buckets(const int* __restrict__ bcnt,
                                                     int* __restrict__ bcur,
                                                     int* __restrict__ bbase) {
    __shared__ int tmp[NBUCKET];
    int t = threadIdx.x;
    int c = bcnt[t];
    tmp[t] = c;
    __syncthreads();
    for (int off = 1; off < NBUCKET; off <<= 1) {
        int add = (t >= off) ? tmp[t - off] : 0;
        __syncthreads();
        tmp[t] += add;
        __syncthreads();
    }
    bcur[t] = tmp[t] - c;
    bbase[t] = tmp[t] - c;
}

// ---- pass 1: bin edges by dst>>7. Per-edge atomics in LDS only; one global
// ---- atomicAdd per (block,bucket) reserves a contiguous run. ----
__global__ __launch_bounds__(1024) void bin_scatter(const int* __restrict__ src,
                                                    const int* __restrict__ dst,
                                                    int* __restrict__ bcur,
                                                    u64* __restrict__ binned) {
    constexpr int REG = BCHUNK / 1024;           // 8 edges per thread
    __shared__ int hist[NBUCKET];                // pass A: counts; pass B: local cursors
    __shared__ int base[NBUCKET];                // global run base for this block
    int t = threadIdx.x;
    int e0 = blockIdx.x * BCHUNK;
    int lim = N_EDGES - e0;

    hist[t] = 0;
    __syncthreads();

    int ds[REG], ss[REG];
#pragma unroll
    for (int i = 0; i < REG; ++i) {
        int idx = t + i * 1024;
        if (idx < lim) {
            ds[i] = dst[e0 + idx];
            ss[i] = src[e0 + idx];
            atomicAdd(&hist[ds[i] >> 7], 1);
        }
    }
    __syncthreads();

    int h = hist[t];
    base[t] = h ? atomicAdd(&bcur[t], h) : 0;    // block-level reservation
    hist[t] = 0;                                 // reuse as local cursor
    __syncthreads();

#pragma unroll
    for (int i = 0; i < REG; ++i) {
        int idx = t + i * 1024;
        if (idx < lim) {
            int b = ds[i] >> 7;
            int pos = base[b] + atomicAdd(&hist[b], 1);
            binned[pos] = (u64)(uint)ss[i] | ((u64)(uint)ds[i] << 32);
        }
    }
}

// ---- pass 2: one block per bucket. LDS count + 128-entry LDS scan -> emits
// ---- row_start, dis, and placed csr_src with ZERO global atomics. ----
__global__ __launch_bounds__(256) void csr_from_bins(const u64* __restrict__ binned,
                                                     const int* __restrict__ bbase,
                                                     const int* __restrict__ bcnt,
                                                     int* __restrict__ row_start,
                                                     float* __restrict__ dis,
                                                     int* __restrict__ csr_src) {
    __shared__ int cnt[128];
    __shared__ int ex[128];
    int t = threadIdx.x;
    int b = blockIdx.x;
    if (t < 128) cnt[t] = 0;
    __syncthreads();
    int start = bbase[b];
    int end = start + bcnt[b];
    for (int i = start + t; i < end; i += 256)
        atomicAdd(&cnt[(int)(uint)(binned[i] >> 32) & 127], 1);
    __syncthreads();
    if (t < 128) ex[t] = cnt[t];
    __syncthreads();
    for (int off = 1; off < 128; off <<= 1) {
        int v = (t < 128 && t >= off) ? ex[t - off] : 0;
        __syncthreads();
        if (t < 128) ex[t] += v;
        __syncthreads();
    }
    if (t < 128) {
        int c = cnt[t];
        ex[t] -= c;                              // exclusive
        int node = b * 128 + t;
        if (node < N_NODES) {
            row_start[node] = start + ex[t];
            dis[node] = rsqrtf((float)(c + 1));  // +1 self-loop
        }
        cnt[t] = 0;                              // reuse as cursor
    }
    if (b == 0 && t == 0) row_start[N_NODES] = N_EDGES;
    __syncthreads();
    for (int i = start + t; i < end; i += 256) {
        u64 p = binned[i];
        int s = (int)(uint)p;
        int d = (int)(uint)(p >> 32) & 127;
        int pos = start + ex[d] + atomicAdd(&cnt[d], 1);
        csr_src[pos] = s;
    }
}

// ---------------- W^T in f16 ----------------
__global__ __launch_bounds__(256) void prep_w(const float* __restrict__ W1,
                                              const float* __restrict__ W2,
                                              f16* __restrict__ wT) {
    int tid = blockIdx.x * 256 + threadIdx.x;
    if (tid < 16384) {                    // W1^T: wT[n*128+k] = W1[k*128+n]
        int n = tid >> 7, k = tid & 127;
        wT[tid] = (f16)W1[k * 128 + n];
    } else if (tid < 24576) {             // W2^T
        int t = tid - 16384;
        int n = t >> 7, k = t & 127;
        wT[tid] = (f16)W2[k * 64 + n];
    }
}

// ---------------- MFMA GEMM layer 1: A = f32 x, scaled by dis, converted while staging ----
__global__ __launch_bounds__(256) void gemm_mfma1(const float* __restrict__ X,
                                                  const float* __restrict__ dis,
                                                  const f16* __restrict__ Bt,
                                                  ushort* __restrict__ Y) {
    constexpr int NT = 8;                 // OUTF = 128
    constexpr int PITCH = 136;
    __shared__ f16 sA[64 * PITCH];
    __shared__ f16 sB[128 * PITCH];
    int tid = threadIdx.x;
    int n0 = blockIdx.x * 64;

    for (int i = tid; i < 64 * 16; i += 256) {
        int r = i >> 4, c = i & 15;
        int n = n0 + r;
        uint4 pk = make_uint4(0, 0, 0, 0);
        if (n < N_NODES) {
            const float4* px = (const float4*)(X + (size_t)n * 128);
            float4 u = px[c * 2], v = px[c * 2 + 1];
            float d = dis[n];
            pk.x = packf16(u.x * d, u.y * d);
            pk.y = packf16(u.z * d, u.w * d);
            pk.z = packf16(v.x * d, v.y * d);
            pk.w = packf16(v.z * d, v.w * d);
        }
        *(uint4*)&sA[r * PITCH + c * 8] = pk;
    }
    for (int i = tid; i < 128 * 16; i += 256) {
        int r = i >> 4, c = i & 15;
        *(uint4*)&sB[r * PITCH + c * 8] = ((const uint4*)(Bt + r * 128))[c];
    }
    __syncthreads();

    int lane = tid & 63, wave = tid >> 6;
    int l15 = lane & 15, q = lane >> 4;
    int m0 = wave * 16;
    f32x4 acc[NT];
#pragma unroll
    for (int nt = 0; nt < NT; ++nt) acc[nt] = (f32x4){0.f, 0.f, 0.f, 0.f};

    const f16* pa = &sA[(m0 + l15) * PITCH + q * 8];
    const f16* pb = &sB[l15 * PITCH + q * 8];
#pragma unroll
    for (int kk = 0; kk < 4; ++kk) {
        f16x8 a = *(const f16x8*)(pa + kk * 32);
#pragma unroll
        for (int nt = 0; nt < NT; ++nt) {
            f16x8 b = *(const f16x8*)(pb + nt * 16 * PITCH + kk * 32);
            acc[nt] = __builtin_amdgcn_mfma_f32_16x16x32_f16(a, b, acc[nt], 0, 0, 0);
        }
    }

    int row_base = n0 + m0 + q * 4;                     // C/D: col=lane&15, row=q*4+reg
#pragma unroll
    for (int nt = 0; nt < NT; ++nt) {
#pragma unroll
        for (int r = 0; r < 4; ++r) {
            int row = row_base + r;
            if (row < N_NODES) {
                union { f16 h; ushort u; } z;
                z.h = (f16)acc[nt][r];
                Y[(size_t)row * 128 + nt * 16 + l15] = z.u;
            }
        }
    }
}

// ---------------- MFMA GEMM (f16 A, K=128): layer 2 ----------------
template <int OUTF>
__global__ __launch_bounds__(256) void gemm_mfma(const f16* __restrict__ A,
                                                 const f16* __restrict__ Bt,
                                                 ushort* __restrict__ Y) {
    constexpr int NT = OUTF / 16;
    constexpr int PITCH = 136;
    __shared__ f16 sA[64 * PITCH];
    __shared__ f16 sB[OUTF * PITCH];
    int tid = threadIdx.x;
    int n0 = blockIdx.x * 64;

    for (int i = tid; i < 64 * 16; i += 256) {
        int r = i >> 4, c = i & 15;
        int n = n0 + r;
        uint4 v = make_uint4(0, 0, 0, 0);
        if (n < N_NODES) v = ((const uint4*)(A + (size_t)n * 128))[c];
        *(uint4*)&sA[r * PITCH + c * 8] = v;
    }
    for (int i = tid; i < OUTF * 16; i += 256) {
        int r = i >> 4, c = i & 15;
        *(uint4*)&sB[r * PITCH + c * 8] = ((const uint4*)(Bt + r * 128))[c];
    }
    __syncthreads();

    int lane = tid & 63, wave = tid >> 6;
    int l15 = lane & 15, q = lane >> 4;
    int m0 = wave * 16;
    f32x4 acc[NT];
#pragma unroll
    for (int nt = 0; nt < NT; ++nt) acc[nt] = (f32x4){0.f, 0.f, 0.f, 0.f};

    const f16* pa = &sA[(m0 + l15) * PITCH + q * 8];
    const f16* pb = &sB[l15 * PITCH + q * 8];
#pragma unroll
    for (int kk = 0; kk < 4; ++kk) {
        f16x8 a = *(const f16x8*)(pa + kk * 32);
#pragma unroll
        for (int nt = 0; nt < NT; ++nt) {
            f16x8 b = *(const f16x8*)(pb + nt * 16 * PITCH + kk * 32);
            acc[nt] = __builtin_amdgcn_mfma_f32_16x16x32_f16(a, b, acc[nt], 0, 0, 0);
        }
    }

    int row_base = n0 + m0 + q * 4;
#pragma unroll
    for (int nt = 0; nt < NT; ++nt) {
#pragma unroll
        for (int r = 0; r < 4; ++r) {
            int row = row_base + r;
            if (row < N_NODES) {
                union { f16 h; ushort u; } z;
                z.h = (f16)acc[nt][r];
                Y[(size_t)row * OUTF + nt * 16 + l15] = z.u;
            }
        }
    }
}

// ---- aggregation L1: half-wave = one 256B row; 2 edges per gather instruction ----
__global__ __launch_bounds__(256) void aggregate1(const ushort* __restrict__ M,
                                                  const int* __restrict__ row_start,
                                                  const int* __restrict__ csr_src,
                                                  const float* __restrict__ dis,
                                                  const float* __restrict__ bias,
                                                  ushort* __restrict__ H1s) {
    int wv = __builtin_amdgcn_readfirstlane((int)(threadIdx.x >> 6));
    int n = blockIdx.x * 4 + wv;
    if (n >= N_NODES) return;
    int lane = threadIdx.x & 63;
    int half = lane >> 5, li = lane & 31;      // li: uint2 index; row = 32 x 8B
    float dn = dis[n];
    int e0 = row_start[n], e1 = row_start[n + 1];
    const uint2* rows = (const uint2*)M;
    float a0, a1, a2, a3;
    {
        uint2 v = rows[(size_t)n * 32 + li];   // self-loop: half 0 only
        float2 f0 = unpackf16(v.x), f1 = unpackf16(v.y);
        bool z = (half == 0);
        a0 = z ? f0.x : 0.f; a1 = z ? f0.y : 0.f;
        a2 = z ? f1.x : 0.f; a3 = z ? f1.y : 0.f;
    }
    int e = e0;
    for (; e + 4 <= e1; e += 4) {
        int sA = csr_src[e + half];
        int sB = csr_src[e + 2 + half];
        uint2 vA = rows[(size_t)sA * 32 + li];
        uint2 vB = rows[(size_t)sB * 32 + li];
        float2 g0 = unpackf16(vA.x), g1 = unpackf16(vA.y);
        float2 h0 = unpackf16(vB.x), h1 = unpackf16(vB.y);
        a0 += g0.x + h0.x; a1 += g0.y + h0.y;
        a2 += g1.x + h1.x; a3 += g1.y + h1.y;
    }
    if (e + 2 <= e1) {
        int s = csr_src[e + half];
        uint2 v = rows[(size_t)s * 32 + li];
        float2 f0 = unpackf16(v.x), f1 = unpackf16(v.y);
        a0 += f0.x; a1 += f0.y; a2 += f1.x; a3 += f1.y;
        e += 2;
    }
    if (e < e1 && half == 0) {
        int s = csr_src[e];
        uint2 v = rows[(size_t)s * 32 + li];
        float2 f0 = unpackf16(v.x), f1 = unpackf16(v.y);
        a0 += f0.x; a1 += f0.y; a2 += f1.x; a3 += f1.y;
    }
    a0 += __shfl_down(a0, 32); a1 += __shfl_down(a1, 32);
    a2 += __shfl_down(a2, 32); a3 += __shfl_down(a3, 32);
    if (half == 0) {
        float4 bb = ((const float4*)bias)[li];  // features 4li..4li+3
        a0 = fmaxf(fmaf(a0, dn, bb.x), 0.f) * dn;
        a1 = fmaxf(fmaf(a1, dn, bb.y), 0.f) * dn;
        a2 = fmaxf(fmaf(a2, dn, bb.z), 0.f) * dn;
        a3 = fmaxf(fmaf(a3, dn, bb.w), 0.f) * dn;
        uint2 o;
        o.x = packf16(a0, a1);
        o.y = packf16(a2, a3);
        ((uint2*)H1s)[(size_t)n * 32 + li] = o;
    }
}

// ---- aggregation L2: quarter-wave = one 128B row; 4 edges per gather instruction ----
__global__ __launch_bounds__(256) void aggregate2(const ushort* __restrict__ M,
                                                  const int* __restrict__ row_start,
                                                  const int* __restrict__ csr_src,
                                                  const float* __restrict__ dis,
                                                  const float* __restrict__ bias,
                                                  float* __restrict__ out) {
    int wv = __builtin_amdgcn_readfirstlane((int)(threadIdx.x >> 6));
    int n = blockIdx.x * 4 + wv;
    if (n >= N_NODES) return;
    int lane = threadIdx.x & 63;
    int q = lane >> 4, li = lane & 15;         // li: uint2 index; row = 16 x 8B
    float dn = dis[n];
    int e0 = row_start[n], e1 = row_start[n + 1];
    const uint2* rows = (const uint2*)M;
    float a0, a1, a2, a3;
    {
        uint2 v = rows[(size_t)n * 16 + li];   // self-loop: quarter 0 only
        float2 f0 = unpackf16(v.x), f1 = unpackf16(v.y);
        bool z = (q == 0);
        a0 = z ? f0.x : 0.f; a1 = z ? f0.y : 0.f;
        a2 = z ? f1.x : 0.f; a3 = z ? f1.y : 0.f;
    }
    int e = e0;
    for (; e + 8 <= e1; e += 8) {
        int sA = csr_src[e + q];
        int sB = csr_src[e + 4 + q];
        uint2 vA = rows[(size_t)sA * 16 + li];
        uint2 vB = rows[(size_t)sB * 16 + li];
        float2 g0 = unpackf16(vA.x), g1 = unpackf16(vA.y);
        float2 h0 = unpackf16(vB.x), h1 = unpackf16(vB.y);
        a0 += g0.x + h0.x; a1 += g0.y + h0.y;
        a2 += g1.x + h1.x; a3 += g1.y + h1.y;
    }
    if (e + 4 <= e1) {
        int s = csr_src[e + q];
        uint2 v = rows[(size_t)s * 16 + li];
        float2 f0 = unpackf16(v.x), f1 = unpackf16(v.y);
        a0 += f0.x; a1 += f0.y; a2 += f1.x; a3 += f1.y;
        e += 4;
    }
    int rem = e1 - e;                          // 0..3
    if (q < rem) {
        int s = csr_src[e + q];
        uint2 v = rows[(size_t)s * 16 + li];
        float2 f0 = unpackf16(v.x), f1 = unpackf16(v.y);
        a0 += f0.x; a1 += f0.y; a2 += f1.x; a3 += f1.y;
    }
    a0 += __shfl_down(a0, 32); a1 += __shfl_down(a1, 32);
    a2 += __shfl_down(a2, 32); a3 += __shfl_down(a3, 32);
    a0 += __shfl_down(a0, 16); a1 += __shfl_down(a1, 16);
    a2 += __shfl_down(a2, 16); a3 += __shfl_down(a3, 16);
    if (q == 0) {
        float4 bb = ((const float4*)bias)[li];
        float4 o;
        o.x = fmaxf(fmaf(a0, dn, bb.x), 0.f);
        o.y = fmaxf(fmaf(a1, dn, bb.y), 0.f);
        o.z = fmaxf(fmaf(a2, dn, bb.z), 0.f);
        o.w = fmaxf(fmaf(a3, dn, bb.w), 0.f);
        ((float4*)out)[(size_t)n * 16 + li] = o;
    }
}

// ---------------- pooling ----------------
__global__ __launch_bounds__(64) void pool_graphs(const float* __restrict__ H,
                                                  const int* __restrict__ batch,
                                                  float* __restrict__ pooled) {
    int g = blockIdx.x;
    int lane = threadIdx.x;
    int lo = 0, hi = N_NODES;
    while (lo < hi) { int mid = (lo + hi) >> 1; if (batch[mid] < g) lo = mid + 1; else hi = mid; }
    int start = lo;
    hi = N_NODES;
    while (lo < hi) { int mid = (lo + hi) >> 1; if (batch[mid] < g + 1) lo = mid + 1; else hi = mid; }
    int end = lo;
    float a0 = 0.f, a1 = 0.f;
    int i = start;
    for (; i + 4 <= end; i += 4) {
        a0 += H[(size_t)i * 64 + lane] + H[(size_t)(i + 1) * 64 + lane];
        a1 += H[(size_t)(i + 2) * 64 + lane] + H[(size_t)(i + 3) * 64 + lane];
    }
    for (; i < end; ++i) a0 += H[(size_t)i * 64 + lane];
    pooled[g * 64 + lane] = a0 + a1;
}

// ---------------- BN batch stats -> scale/shift ----------------
__global__ __launch_bounds__(64) void bn_stats(const float* __restrict__ pooled,
                                               const float* __restrict__ gamma,
                                               const float* __restrict__ beta,
                                               float* __restrict__ scale,
                                               float* __restrict__ shift) {
    int f = threadIdx.x;
    float s = 0.f, s2 = 0.f;
    for (int g = 0; g < N_GRAPHS; ++g) {
        float v = pooled[g * 64 + f];
        s += v;
        s2 = fmaf(v, v, s2);
    }
    float mean = s * (1.0f / N_GRAPHS);
    float var = s2 * (1.0f / N_GRAPHS) - mean * mean;
    float istd = rsqrtf(var + BN_EPS);
    float sc = gamma[f] * istd;
    scale[f] = sc;
    shift[f] = beta[f] - mean * sc;
}

// ---------------- head ----------------
__global__ __launch_bounds__(256) void head(const float* __restrict__ pooled,
                                            const float* __restrict__ scale,
                                            const float* __restrict__ shift,
                                            const float* __restrict__ Wo1,
                                            const float* __restrict__ bo1,
                                            const float* __restrict__ Wo2,
                                            const float* __restrict__ bo2,
                                            float* __restrict__ out) {
    __shared__ float sW1[64 * 24];
    __shared__ float sW2[24];
    __shared__ float sb1[24];
    __shared__ float ssc[64];
    __shared__ float ssh[64];
    int tid = threadIdx.x;
    for (int i = tid; i < 64 * 24; i += 256) sW1[i] = Wo1[i];
    if (tid < 24) { sW2[tid] = Wo2[tid]; sb1[tid] = bo1[tid]; }
    if (tid < 64) { ssc[tid] = scale[tid]; ssh[tid] = shift[tid]; }
    __syncthreads();
    int g = blockIdx.x * 256 + tid;
    if (g >= N_GRAPHS) return;
    float xn[64];
    const float* pr = pooled + g * 64;
#pragma unroll
    for (int j = 0; j < 64; ++j) xn[j] = fmaf(pr[j], ssc[j], ssh[j]);
    float o = bo2[0];
#pragma unroll 4
    for (int k = 0; k < 24; ++k) {
        float h = sb1[k];
#pragma unroll
        for (int j = 0; j < 64; ++j) h = fmaf(xn[j], sW1[j * 24 + k], h);
        o = fmaf(fmaxf(h, 0.f), sW2[k], o);
    }
    out[g] = o;
}

extern "C" void kernel_launch(void* const* d_in, const int* in_sizes, int n_in,
                              void* d_out, int out_size, void* d_ws, size_t ws_size,
                              hipStream_t stream) {
    const float* x     = (const float*)d_in[0];
    const int*   ei    = (const int*)d_in[1];   // [2,E]: first E = src, next E = dst
    const int*   batch = (const int*)d_in[2];
    const float* W1    = (const float*)d_in[3];
    const float* b1    = (const float*)d_in[4];
    const float* W2    = (const float*)d_in[5];
    const float* b2    = (const float*)d_in[6];
    const float* gamma = (const float*)d_in[7];
    const float* beta  = (const float*)d_in[8];
    const float* Wo1   = (const float*)d_in[9];
    const float* bo1   = (const float*)d_in[10];
    const float* Wo2   = (const float*)d_in[11];
    const float* bo2   = (const float*)d_in[12];
    float* out = (float*)d_out;               // [512] out, then [512*64] h(=pooled)
    char* ws = (char*)d_ws;

    const int* srcv = ei;
    const int* dstv = ei + N_EDGES;
    int*    bcnt     = (int*)(ws + OFF_BCNT);
    int*    bcur     = (int*)(ws + OFF_BCUR);
    int*    bbase    = (int*)(ws + OFF_BBASE);
    float*  dis      = (float*)(ws + OFF_DIS);
    int*    row_start= (int*)(ws + OFF_ROW);
    float*  scale    = (float*)(ws + OFF_SC);
    float*  shift    = (float*)(ws + OFF_SH);
    f16*    wT       = (f16*)(ws + OFF_WT);
    int*    csr_src  = (int*)(ws + OFF_CSR);
    f16*    bufP     = (f16*)(ws + OFF_P);    // h1s(f16) -> h2(f32)
    ushort* bufQ     = (ushort*)(ws + OFF_Q); // binned(u64, early) -> M1 -> M2
    u64*    binned   = (u64*)(ws + OFF_Q);
    float*  pooled   = out + N_GRAPHS;        // h output region, also used downstream

    hipMemsetAsync(ws + OFF_BCNT, 0, 4096, stream);

    bucket_hist<<<256, 256, 0, stream>>>(dstv, bcnt);
    scan_buckets<<<1, NBUCKET, 0, stream>>>(bcnt, bcur, bbase);
    bin_scatter<<<NCHUNKS, 1024, 0, stream>>>(srcv, dstv, bcur, binned);
    csr_from_bins<<<NBUCKET_USED, 256, 0, stream>>>(binned, bbase, bcnt, row_start, dis, csr_src);

    prep_w<<<96, 256, 0, stream>>>(W1, W2, wT);

    int gblocks = (N_NODES + 63) / 64;
    int ablocks = (N_NODES + 3) / 4;
    gemm_mfma1<<<gblocks, 256, 0, stream>>>(x, dis, wT, bufQ);
    aggregate1<<<ablocks, 256, 0, stream>>>(bufQ, row_start, csr_src, dis, b1, (ushort*)bufP);
    gemm_mfma<64><<<gblocks, 256, 0, stream>>>(bufP, wT + 16384, bufQ);
    aggregate2<<<ablocks, 256, 0, stream>>>(bufQ, row_start, csr_src, dis, b2, (float*)bufP);

    pool_graphs<<<N_GRAPHS, 64, 0, stream>>>((float*)bufP, batch, pooled);
    bn_stats<<<1, 64, 0, stream>>>(pooled, gamma, beta, scale, shift);
    head<<<2, 256, 0, stream>>>(pooled, scale, shift, Wo1, bo1, Wo2, bo2, out);
}

// Round 8
// 337.598 us; speedup vs baseline: 2.4652x; 1.0920x over previous
//
#include <hip/hip_runtime.h>
#include <math.h>

#define N_NODES 100000
#define N_EDGES 1600000
#define N_GRAPHS 512
#define BN_EPS 1e-5f

#define NBUCKET 1024                            // dst>>7 -> 782 used
#define NBUCKET_USED ((N_NODES + 127) / 128)    // 782
#define BCHUNK 8192                             // edges per bin_scatter block
#define NCHUNKS ((N_EDGES + BCHUNK - 1) / BCHUNK)  // 196

typedef unsigned int uint;
typedef unsigned short ushort;
typedef _Float16 f16;
typedef _Float16 f16x8 __attribute__((ext_vector_type(8)));
typedef float f32x4 __attribute__((ext_vector_type(4)));

// ---------------- workspace layout (bytes) ----------------
constexpr size_t OFF_BCNT  = 0;          // int[1024] bucket counts        (memset)
constexpr size_t OFF_BCUR  = 4096;       // int[1024] bucket cursors
constexpr size_t OFF_BBASE = 8192;       // int[1024] bucket exclusive bases
constexpr size_t OFF_DIS   = 12288;      // float[N] rsqrt(deg+1)
constexpr size_t OFF_ROW   = 412288;     // int[N+1] CSR row starts
constexpr size_t OFF_SC    = 812416;     // float[64] BN scale
constexpr size_t OFF_SH    = 812672;     // float[64] BN shift
constexpr size_t OFF_WT    = 812928;     // f16[128*128 + 64*128] W1^T,W2^T
constexpr size_t OFF_CSR   = 862080;     // int[E] CSR src indices
constexpr size_t OFF_P     = 7262080;    // 25.6MB: h1s(f16) -> h2(f32)
constexpr size_t OFF_Q     = 32862080;   // 25.6MB: binned(uint, early) -> M1/M2(f16)

__device__ __forceinline__ uint packf16(float a, float b) {
    union { f16 h[2]; uint u; } z;
    z.h[0] = (f16)a; z.h[1] = (f16)b;
    return z.u;
}
__device__ __forceinline__ float2 unpackf16(uint u) {
    union { uint u; f16 h[2]; } z;
    z.u = u;
    return make_float2((float)z.h[0], (float)z.h[1]);
}

// ---------------- bucket histogram (LDS only) ----------------
__global__ __launch_bounds__(256) void bucket_hist(const int* __restrict__ dst,
                                                   int* __restrict__ bcnt) {
    __shared__ int h[NBUCKET];
    for (int i = threadIdx.x; i < NBUCKET; i += 256) h[i] = 0;
    __syncthreads();
    int stride = gridDim.x * 256;
    for (int e = blockIdx.x * 256 + threadIdx.x; e < N_EDGES; e += stride)
        atomicAdd(&h[dst[e] >> 7], 1);
    __syncthreads();
    for (int i = threadIdx.x; i < NBUCKET; i += 256) {
        int v = h[i];
        if (v) atomicAdd(&bcnt[i], v);
    }
}

// ---------------- bucket scan -> exclusive bases (bcur = working cursor copy) ----------------
__global__ __launch_bounds__(1024) void scan_buckets(const int* __restrict__ bcnt,
                                                     int* __restrict__ bcur,
                                                     int* __restrict__ bbase) {
    __shared__ int tmp[NBUCKET];
    int t = threadIdx.x;
    int c = bcnt[t];
    tmp[t] = c;
    __syncthreads();
    for (int off = 1; off < NBUCKET; off <<= 1) {
        int add = (t >= off) ? tmp[t - off] : 0;
        __syncthreads();
        tmp[t] += add;
        __syncthreads();
    }
    bcur[t] = tmp[t] - c;
    bbase[t] = tmp[t] - c;
}

// ---- pass 1: bin edges by dst>>7. Payload packed in uint: src<<7 | (dst&127). ----
__global__ __launch_bounds__(1024) void bin_scatter(const int* __restrict__ src,
                                                    const int* __restrict__ dst,
                                                    int* __restrict__ bcur,
                                                    uint* __restrict__ binned) {
    constexpr int REG = BCHUNK / 1024;           // 8 edges per thread
    __shared__ int hist[NBUCKET];                // pass A: counts; pass B: local cursors
    __shared__ int base[NBUCKET];                // global run base for this block
    int t = threadIdx.x;
    int e0 = blockIdx.x * BCHUNK;
    int lim = N_EDGES - e0;

    hist[t] = 0;
    __syncthreads();

    int ds[REG], ss[REG];
#pragma unroll
    for (int i = 0; i < REG; ++i) {
        int idx = t + i * 1024;
        if (idx < lim) {
            ds[i] = dst[e0 + idx];
            ss[i] = src[e0 + idx];
            atomicAdd(&hist[ds[i] >> 7], 1);
        }
    }
    __syncthreads();

    int h = hist[t];
    base[t] = h ? atomicAdd(&bcur[t], h) : 0;    // block-level reservation
    hist[t] = 0;                                 // reuse as local cursor
    __syncthreads();

#pragma unroll
    for (int i = 0; i < REG; ++i) {
        int idx = t + i * 1024;
        if (idx < lim) {
            int b = ds[i] >> 7;
            int pos = base[b] + atomicAdd(&hist[b], 1);
            binned[pos] = ((uint)ss[i] << 7) | (uint)(ds[i] & 127);
        }
    }
}

// ---- pass 2: one block per bucket. LDS count + scan -> row_start, dis, placed csr_src. ----
__global__ __launch_bounds__(256) void csr_from_bins(const uint* __restrict__ binned,
                                                     const int* __restrict__ bbase,
                                                     const int* __restrict__ bcnt,
                                                     int* __restrict__ row_start,
                                                     float* __restrict__ dis,
                                                     int* __restrict__ csr_src) {
    __shared__ int cnt[128];
    __shared__ int ex[128];
    int t = threadIdx.x;
    int b = blockIdx.x;
    if (t < 128) cnt[t] = 0;
    __syncthreads();
    int start = bbase[b];
    int end = start + bcnt[b];
    for (int i = start + t; i < end; i += 256)
        atomicAdd(&cnt[binned[i] & 127u], 1);
    __syncthreads();
    if (t < 128) ex[t] = cnt[t];
    __syncthreads();
    for (int off = 1; off < 128; off <<= 1) {
        int v = (t < 128 && t >= off) ? ex[t - off] : 0;
        __syncthreads();
        if (t < 128) ex[t] += v;
        __syncthreads();
    }
    if (t < 128) {
        int c = cnt[t];
        ex[t] -= c;                              // exclusive
        int node = b * 128 + t;
        if (node < N_NODES) {
            row_start[node] = start + ex[t];
            dis[node] = rsqrtf((float)(c + 1));  // +1 self-loop
        }
        cnt[t] = 0;                              // reuse as cursor
    }
    if (b == 0 && t == 0) row_start[N_NODES] = N_EDGES;
    __syncthreads();
    for (int i = start + t; i < end; i += 256) {
        uint p = binned[i];
        int s = (int)(p >> 7);
        int d = (int)(p & 127u);
        int pos = start + ex[d] + atomicAdd(&cnt[d], 1);
        csr_src[pos] = s;
    }
}

// ---------------- W^T in f16 ----------------
__global__ __launch_bounds__(256) void prep_w(const float* __restrict__ W1,
                                              const float* __restrict__ W2,
                                              f16* __restrict__ wT) {
    int tid = blockIdx.x * 256 + threadIdx.x;
    if (tid < 16384) {                    // W1^T: wT[n*128+k] = W1[k*128+n]
        int n = tid >> 7, k = tid & 127;
        wT[tid] = (f16)W1[k * 128 + n];
    } else if (tid < 24576) {             // W2^T
        int t = tid - 16384;
        int n = t >> 7, k = t & 127;
        wT[tid] = (f16)W2[k * 64 + n];
    }
}

// ---------------- MFMA GEMM layer 1: A = f32 x, scaled by dis, converted while staging ----
__global__ __launch_bounds__(256) void gemm_mfma1(const float* __restrict__ X,
                                                  const float* __restrict__ dis,
                                                  const f16* __restrict__ Bt,
                                                  ushort* __restrict__ Y) {
    constexpr int NT = 8;                 // OUTF = 128
    constexpr int PITCH = 136;
    __shared__ f16 sA[64 * PITCH];
    __shared__ f16 sB[128 * PITCH];
    int tid = threadIdx.x;
    int n0 = blockIdx.x * 64;

    for (int i = tid; i < 64 * 16; i += 256) {
        int r = i >> 4, c = i & 15;
        int n = n0 + r;
        uint4 pk = make_uint4(0, 0, 0, 0);
        if (n < N_NODES) {
            const float4* px = (const float4*)(X + (size_t)n * 128);
            float4 u = px[c * 2], v = px[c * 2 + 1];
            float d = dis[n];
            pk.x = packf16(u.x * d, u.y * d);
            pk.y = packf16(u.z * d, u.w * d);
            pk.z = packf16(v.x * d, v.y * d);
            pk.w = packf16(v.z * d, v.w * d);
        }
        *(uint4*)&sA[r * PITCH + c * 8] = pk;
    }
    for (int i = tid; i < 128 * 16; i += 256) {
        int r = i >> 4, c = i & 15;
        *(uint4*)&sB[r * PITCH + c * 8] = ((const uint4*)(Bt + r * 128))[c];
    }
    __syncthreads();

    int lane = tid & 63, wave = tid >> 6;
    int l15 = lane & 15, q = lane >> 4;
    int m0 = wave * 16;
    f32x4 acc[NT];
#pragma unroll
    for (int nt = 0; nt < NT; ++nt) acc[nt] = (f32x4){0.f, 0.f, 0.f, 0.f};

    const f16* pa = &sA[(m0 + l15) * PITCH + q * 8];
    const f16* pb = &sB[l15 * PITCH + q * 8];
#pragma unroll
    for (int kk = 0; kk < 4; ++kk) {
        f16x8 a = *(const f16x8*)(pa + kk * 32);
#pragma unroll
        for (int nt = 0; nt < NT; ++nt) {
            f16x8 b = *(const f16x8*)(pb + nt * 16 * PITCH + kk * 32);
            acc[nt] = __builtin_amdgcn_mfma_f32_16x16x32_f16(a, b, acc[nt], 0, 0, 0);
        }
    }

    int row_base = n0 + m0 + q * 4;                     // C/D: col=lane&15, row=q*4+reg
#pragma unroll
    for (int nt = 0; nt < NT; ++nt) {
#pragma unroll
        for (int r = 0; r < 4; ++r) {
            int row = row_base + r;
            if (row < N_NODES) {
                union { f16 h; ushort u; } z;
                z.h = (f16)acc[nt][r];
                Y[(size_t)row * 128 + nt * 16 + l15] = z.u;
            }
        }
    }
}

// ---------------- MFMA GEMM (f16 A, K=128): layer 2 ----------------
template <int OUTF>
__global__ __launch_bounds__(256) void gemm_mfma(const f16* __restrict__ A,
                                                 const f16* __restrict__ Bt,
                                                 ushort* __restrict__ Y) {
    constexpr int NT = OUTF / 16;
    constexpr int PITCH = 136;
    __shared__ f16 sA[64 * PITCH];
    __shared__ f16 sB[OUTF * PITCH];
    int tid = threadIdx.x;
    int n0 = blockIdx.x * 64;

    for (int i = tid; i < 64 * 16; i += 256) {
        int r = i >> 4, c = i & 15;
        int n = n0 + r;
        uint4 v = make_uint4(0, 0, 0, 0);
        if (n < N_NODES) v = ((const uint4*)(A + (size_t)n * 128))[c];
        *(uint4*)&sA[r * PITCH + c * 8] = v;
    }
    for (int i = tid; i < OUTF * 16; i += 256) {
        int r = i >> 4, c = i & 15;
        *(uint4*)&sB[r * PITCH + c * 8] = ((const uint4*)(Bt + r * 128))[c];
    }
    __syncthreads();

    int lane = tid & 63, wave = tid >> 6;
    int l15 = lane & 15, q = lane >> 4;
    int m0 = wave * 16;
    f32x4 acc[NT];
#pragma unroll
    for (int nt = 0; nt < NT; ++nt) acc[nt] = (f32x4){0.f, 0.f, 0.f, 0.f};

    const f16* pa = &sA[(m0 + l15) * PITCH + q * 8];
    const f16* pb = &sB[l15 * PITCH + q * 8];
#pragma unroll
    for (int kk = 0; kk < 4; ++kk) {
        f16x8 a = *(const f16x8*)(pa + kk * 32);
#pragma unroll
        for (int nt = 0; nt < NT; ++nt) {
            f16x8 b = *(const f16x8*)(pb + nt * 16 * PITCH + kk * 32);
            acc[nt] = __builtin_amdgcn_mfma_f32_16x16x32_f16(a, b, acc[nt], 0, 0, 0);
        }
    }

    int row_base = n0 + m0 + q * 4;
#pragma unroll
    for (int nt = 0; nt < NT; ++nt) {
#pragma unroll
        for (int r = 0; r < 4; ++r) {
            int row = row_base + r;
            if (row < N_NODES) {
                union { f16 h; ushort u; } z;
                z.h = (f16)acc[nt][r];
                Y[(size_t)row * OUTF + nt * 16 + l15] = z.u;
            }
        }
    }
}

// ---- aggregation L1: full-wave 256B row gathers, 8 edges in flight ----
__global__ __launch_bounds__(256) void aggregate1(const ushort* __restrict__ M,
                                                  const int* __restrict__ row_start,
                                                  const int* __restrict__ csr_src,
                                                  const float* __restrict__ dis,
                                                  const float* __restrict__ bias,
                                                  ushort* __restrict__ H1s) {
    int wv = __builtin_amdgcn_readfirstlane((int)(threadIdx.x >> 6));
    int n = blockIdx.x * 4 + wv;
    if (n >= N_NODES) return;
    int lane = threadIdx.x & 63;
    float dn = dis[n];
    int e0 = row_start[n], e1 = row_start[n + 1];
    const uint* rows = (const uint*)M;                  // 64 uints (=128 f16) per row
    float2 t0 = unpackf16(rows[(size_t)n * 64 + lane]); // self-loop term
    float a0 = t0.x, a1 = t0.y, b0 = 0.f, b1v = 0.f;
    int e = e0;
    for (; e + 8 <= e1; e += 8) {
        int s0 = csr_src[e], s1 = csr_src[e + 1], s2 = csr_src[e + 2], s3 = csr_src[e + 3];
        int s4 = csr_src[e + 4], s5 = csr_src[e + 5], s6 = csr_src[e + 6], s7 = csr_src[e + 7];
        uint v0 = rows[(size_t)s0 * 64 + lane];
        uint v1 = rows[(size_t)s1 * 64 + lane];
        uint v2 = rows[(size_t)s2 * 64 + lane];
        uint v3 = rows[(size_t)s3 * 64 + lane];
        uint v4 = rows[(size_t)s4 * 64 + lane];
        uint v5 = rows[(size_t)s5 * 64 + lane];
        uint v6 = rows[(size_t)s6 * 64 + lane];
        uint v7 = rows[(size_t)s7 * 64 + lane];
        float2 f0 = unpackf16(v0), f1 = unpackf16(v1), f2 = unpackf16(v2), f3 = unpackf16(v3);
        float2 f4 = unpackf16(v4), f5 = unpackf16(v5), f6 = unpackf16(v6), f7 = unpackf16(v7);
        a0 += f0.x + f1.x; a1 += f0.y + f1.y;
        b0 += f2.x + f3.x; b1v += f2.y + f3.y;
        a0 += f4.x + f5.x; a1 += f4.y + f5.y;
        b0 += f6.x + f7.x; b1v += f6.y + f7.y;
    }
    for (; e + 4 <= e1; e += 4) {
        int s0 = csr_src[e], s1 = csr_src[e + 1], s2 = csr_src[e + 2], s3 = csr_src[e + 3];
        uint v0 = rows[(size_t)s0 * 64 + lane];
        uint v1 = rows[(size_t)s1 * 64 + lane];
        uint v2 = rows[(size_t)s2 * 64 + lane];
        uint v3 = rows[(size_t)s3 * 64 + lane];
        float2 f0 = unpackf16(v0), f1 = unpackf16(v1), f2 = unpackf16(v2), f3 = unpackf16(v3);
        a0 += f0.x + f1.x; a1 += f0.y + f1.y;
        b0 += f2.x + f3.x; b1v += f2.y + f3.y;
    }
    for (; e < e1; ++e) {
        float2 f = unpackf16(rows[(size_t)csr_src[e] * 64 + lane]);
        a0 += f.x; a1 += f.y;
    }
    a0 += b0; a1 += b1v;
    a0 = fmaxf(fmaf(a0, dn, bias[2 * lane]), 0.f) * dn;
    a1 = fmaxf(fmaf(a1, dn, bias[2 * lane + 1]), 0.f) * dn;
    ((uint*)H1s)[(size_t)n * 64 + lane] = packf16(a0, a1);
}

// ---- aggregation L2: full-wave 128B row gathers (ushort/lane), 8 edges in flight ----
__global__ __launch_bounds__(256) void aggregate2(const ushort* __restrict__ M,
                                                  const int* __restrict__ row_start,
                                                  const int* __restrict__ csr_src,
                                                  const float* __restrict__ dis,
                                                  const float* __restrict__ bias,
                                                  float* __restrict__ out) {
    int wv = __builtin_amdgcn_readfirstlane((int)(threadIdx.x >> 6));
    int n = blockIdx.x * 4 + wv;
    if (n >= N_NODES) return;
    int lane = threadIdx.x & 63;
    float dn = dis[n];
    int e0 = row_start[n], e1 = row_start[n + 1];
    const f16* rows = (const f16*)M;
    float a0 = (float)rows[(size_t)n * 64 + lane];      // self-loop term
    float a1 = 0.f;
    int e = e0;
    for (; e + 8 <= e1; e += 8) {
        int s0 = csr_src[e], s1 = csr_src[e + 1], s2 = csr_src[e + 2], s3 = csr_src[e + 3];
        int s4 = csr_src[e + 4], s5 = csr_src[e + 5], s6 = csr_src[e + 6], s7 = csr_src[e + 7];
        float v0 = (float)rows[(size_t)s0 * 64 + lane];
        float v1 = (float)rows[(size_t)s1 * 64 + lane];
        float v2 = (float)rows[(size_t)s2 * 64 + lane];
        float v3 = (float)rows[(size_t)s3 * 64 + lane];
        float v4 = (float)rows[(size_t)s4 * 64 + lane];
        float v5 = (float)rows[(size_t)s5 * 64 + lane];
        float v6 = (float)rows[(size_t)s6 * 64 + lane];
        float v7 = (float)rows[(size_t)s7 * 64 + lane];
        a0 += v0 + v1; a1 += v2 + v3;
        a0 += v4 + v5; a1 += v6 + v7;
    }
    for (; e + 4 <= e1; e += 4) {
        int s0 = csr_src[e], s1 = csr_src[e + 1], s2 = csr_src[e + 2], s3 = csr_src[e + 3];
        float v0 = (float)rows[(size_t)s0 * 64 + lane];
        float v1 = (float)rows[(size_t)s1 * 64 + lane];
        float v2 = (float)rows[(size_t)s2 * 64 + lane];
        float v3 = (float)rows[(size_t)s3 * 64 + lane];
        a0 += v0 + v1; a1 += v2 + v3;
    }
    for (; e < e1; ++e) a0 += (float)rows[(size_t)csr_src[e] * 64 + lane];
    a0 += a1;
    a0 = fmaf(a0, dn, bias[lane]);
    out[(size_t)n * 64 + lane] = fmaxf(a0, 0.f);
}

// ---------------- pooling ----------------
__global__ __launch_bounds__(64) void pool_graphs(const float* __restrict__ H,
                                                  const int* __restrict__ batch,
                                                  float* __restrict__ pooled) {
    int g = blockIdx.x;
    int lane = threadIdx.x;
    int lo = 0, hi = N_NODES;
    while (lo < hi) { int mid = (lo + hi) >> 1; if (batch[mid] < g) lo = mid + 1; else hi = mid; }
    int start = lo;
    hi = N_NODES;
    while (lo < hi) { int mid = (lo + hi) >> 1; if (batch[mid] < g + 1) lo = mid + 1; else hi = mid; }
    int end = lo;
    float a0 = 0.f, a1 = 0.f;
    int i = start;
    for (; i + 4 <= end; i += 4) {
        a0 += H[(size_t)i * 64 + lane] + H[(size_t)(i + 1) * 64 + lane];
        a1 += H[(size_t)(i + 2) * 64 + lane] + H[(size_t)(i + 3) * 64 + lane];
    }
    for (; i < end; ++i) a0 += H[(size_t)i * 64 + lane];
    pooled[g * 64 + lane] = a0 + a1;
}

// ---------------- BN batch stats -> scale/shift ----------------
__global__ __launch_bounds__(64) void bn_stats(const float* __restrict__ pooled,
                                               const float* __restrict__ gamma,
                                               const float* __restrict__ beta,
                                               float* __restrict__ scale,
                                               float* __restrict__ shift) {
    int f = threadIdx.x;
    float s = 0.f, s2 = 0.f;
    for (int g = 0; g < N_GRAPHS; ++g) {
        float v = pooled[g * 64 + f];
        s += v;
        s2 = fmaf(v, v, s2);
    }
    float mean = s * (1.0f / N_GRAPHS);
    float var = s2 * (1.0f / N_GRAPHS) - mean * mean;
    float istd = rsqrtf(var + BN_EPS);
    float sc = gamma[f] * istd;
    scale[f] = sc;
    shift[f] = beta[f] - mean * sc;
}

// ---------------- head ----------------
__global__ __launch_bounds__(256) void head(const float* __restrict__ pooled,
                                            const float* __restrict__ scale,
                                            const float* __restrict__ shift,
                                            const float* __restrict__ Wo1,
                                            const float* __restrict__ bo1,
                                            const float* __restrict__ Wo2,
                                            const float* __restrict__ bo2,
                                            float* __restrict__ out) {
    __shared__ float sW1[64 * 24];
    __shared__ float sW2[24];
    __shared__ float sb1[24];
    __shared__ float ssc[64];
    __shared__ float ssh[64];
    int tid = threadIdx.x;
    for (int i = tid; i < 64 * 24; i += 256) sW1[i] = Wo1[i];
    if (tid < 24) { sW2[tid] = Wo2[tid]; sb1[tid] = bo1[tid]; }
    if (tid < 64) { ssc[tid] = scale[tid]; ssh[tid] = shift[tid]; }
    __syncthreads();
    int g = blockIdx.x * 256 + tid;
    if (g >= N_GRAPHS) return;
    float xn[64];
    const float* pr = pooled + g * 64;
#pragma unroll
    for (int j = 0; j < 64; ++j) xn[j] = fmaf(pr[j], ssc[j], ssh[j]);
    float o = bo2[0];
#pragma unroll 4
    for (int k = 0; k < 24; ++k) {
        float h = sb1[k];
#pragma unroll
        for (int j = 0; j < 64; ++j) h = fmaf(xn[j], sW1[j * 24 + k], h);
        o = fmaf(fmaxf(h, 0.f), sW2[k], o);
    }
    out[g] = o;
}

extern "C" void kernel_launch(void* const* d_in, const int* in_sizes, int n_in,
                              void* d_out, int out_size, void* d_ws, size_t ws_size,
                              hipStream_t stream) {
    const float* x     = (const float*)d_in[0];
    const int*   ei    = (const int*)d_in[1];   // [2,E]: first E = src, next E = dst
    const int*   batch = (const int*)d_in[2];
    const float* W1    = (const float*)d_in[3];
    const float* b1    = (const float*)d_in[4];
    const float* W2    = (const float*)d_in[5];
    const float* b2    = (const float*)d_in[6];
    const float* gamma = (const float*)d_in[7];
    const float* beta  = (const float*)d_in[8];
    const float* Wo1   = (const float*)d_in[9];
    const float* bo1   = (const float*)d_in[10];
    const float* Wo2   = (const float*)d_in[11];
    const float* bo2   = (const float*)d_in[12];
    float* out = (float*)d_out;               // [512] out, then [512*64] h(=pooled)
    char* ws = (char*)d_ws;

    const int* srcv = ei;
    const int* dstv = ei + N_EDGES;
    int*    bcnt     = (int*)(ws + OFF_BCNT);
    int*    bcur     = (int*)(ws + OFF_BCUR);
    int*    bbase    = (int*)(ws + OFF_BBASE);
    float*  dis      = (float*)(ws + OFF_DIS);
    int*    row_start= (int*)(ws + OFF_ROW);
    float*  scale    = (float*)(ws + OFF_SC);
    float*  shift    = (float*)(ws + OFF_SH);
    f16*    wT       = (f16*)(ws + OFF_WT);
    int*    csr_src  = (int*)(ws + OFF_CSR);
    f16*    bufP     = (f16*)(ws + OFF_P);    // h1s(f16) -> h2(f32)
    ushort* bufQ     = (ushort*)(ws + OFF_Q); // binned(uint, early) -> M1 -> M2
    uint*   binned   = (uint*)(ws + OFF_Q);
    float*  pooled   = out + N_GRAPHS;        // h output region, also used downstream

    hipMemsetAsync(ws + OFF_BCNT, 0, 4096, stream);

    bucket_hist<<<256, 256, 0, stream>>>(dstv, bcnt);
    scan_buckets<<<1, NBUCKET, 0, stream>>>(bcnt, bcur, bbase);
    bin_scatter<<<NCHUNKS, 1024, 0, stream>>>(srcv, dstv, bcur, binned);
    csr_from_bins<<<NBUCKET_USED, 256, 0, stream>>>(binned, bbase, bcnt, row_start, dis, csr_src);

    prep_w<<<96, 256, 0, stream>>>(W1, W2, wT);

    int gblocks = (N_NODES + 63) / 64;
    int ablocks = (N_NODES + 3) / 4;
    gemm_mfma1<<<gblocks, 256, 0, stream>>>(x, dis, wT, bufQ);
    aggregate1<<<ablocks, 256, 0, stream>>>(bufQ, row_start, csr_src, dis, b1, (ushort*)bufP);
    gemm_mfma<64><<<gblocks, 256, 0, stream>>>(bufP, wT + 16384, bufQ);
    aggregate2<<<ablocks, 256, 0, stream>>>(bufQ, row_start, csr_src, dis, b2, (float*)bufP);

    pool_graphs<<<N_GRAPHS, 64, 0, stream>>>((float*)bufP, batch, pooled);
    bn_stats<<<1, 64, 0, stream>>>(pooled, gamma, beta, scale, shift);
    head<<<2, 256, 0, stream>>>(pooled, scale, shift, Wo1, bo1, Wo2, bo2, out);
}

// Round 9
// 335.960 us; speedup vs baseline: 2.4773x; 1.0049x over previous
//
#include <hip/hip_runtime.h>
#include <math.h>

#define N_NODES 100000
#define N_EDGES 1600000
#define N_GRAPHS 512
#define BN_EPS 1e-5f

#define NBUCKET 1024                            // dst>>7 -> 782 used
#define NBUCKET_USED ((N_NODES + 127) / 128)    // 782
#define BCHUNK 8192                             // edges per bin_scatter block
#define NCHUNKS ((N_EDGES + BCHUNK - 1) / BCHUNK)  // 196

typedef unsigned int uint;
typedef unsigned short ushort;
typedef _Float16 f16;
typedef _Float16 f16x8 __attribute__((ext_vector_type(8)));
typedef float f32x4 __attribute__((ext_vector_type(4)));

// ---------------- workspace layout (bytes) ----------------
constexpr size_t OFF_BCNT  = 0;          // int[1024] bucket counts        (memset)
constexpr size_t OFF_BCUR  = 4096;       // int[1024] bucket cursors
constexpr size_t OFF_BBASE = 8192;       // int[1024] bucket exclusive bases
constexpr size_t OFF_DIS   = 12288;      // float[N] rsqrt(deg+1)
constexpr size_t OFF_ROW   = 412288;     // int[N+1] CSR row starts
constexpr size_t OFF_SC    = 812416;     // float[64] BN scale
constexpr size_t OFF_SH    = 812672;     // float[64] BN shift
constexpr size_t OFF_WT    = 812928;     // f16[128*128 + 64*128] W1^T,W2^T
constexpr size_t OFF_CSR   = 862080;     // int[E] CSR src indices
constexpr size_t OFF_P     = 7262080;    // 25.6MB: h1s(f16) -> h2(f32)
constexpr size_t OFF_Q     = 32862080;   // 25.6MB: binned(uint, early) -> M1/M2(f16)

__device__ __forceinline__ uint packf16(float a, float b) {
    union { f16 h[2]; uint u; } z;
    z.h[0] = (f16)a; z.h[1] = (f16)b;
    return z.u;
}
__device__ __forceinline__ float2 unpackf16(uint u) {
    union { uint u; f16 h[2]; } z;
    z.u = u;
    return make_float2((float)z.h[0], (float)z.h[1]);
}

// ---------------- bucket histogram (LDS only) ----------------
__global__ __launch_bounds__(256) void bucket_hist(const int* __restrict__ dst,
                                                   int* __restrict__ bcnt) {
    __shared__ int h[NBUCKET];
    for (int i = threadIdx.x; i < NBUCKET; i += 256) h[i] = 0;
    __syncthreads();
    int stride = gridDim.x * 256;
    for (int e = blockIdx.x * 256 + threadIdx.x; e < N_EDGES; e += stride)
        atomicAdd(&h[dst[e] >> 7], 1);
    __syncthreads();
    for (int i = threadIdx.x; i < NBUCKET; i += 256) {
        int v = h[i];
        if (v) atomicAdd(&bcnt[i], v);
    }
}

// ---------------- bucket scan -> exclusive bases (bcur = working cursor copy) ----------------
__global__ __launch_bounds__(1024) void scan_buckets(const int* __restrict__ bcnt,
                                                     int* __restrict__ bcur,
                                                     int* __restrict__ bbase) {
    __shared__ int tmp[NBUCKET];
    int t = threadIdx.x;
    int c = bcnt[t];
    tmp[t] = c;
    __syncthreads();
    for (int off = 1; off < NBUCKET; off <<= 1) {
        int add = (t >= off) ? tmp[t - off] : 0;
        __syncthreads();
        tmp[t] += add;
        __syncthreads();
    }
    bcur[t] = tmp[t] - c;
    bbase[t] = tmp[t] - c;
}

// ---- pass 1: bin edges by dst>>7. Payload packed in uint: src<<7 | (dst&127). ----
__global__ __launch_bounds__(1024) void bin_scatter(const int* __restrict__ src,
                                                    const int* __restrict__ dst,
                                                    int* __restrict__ bcur,
                                                    uint* __restrict__ binned) {
    constexpr int REG = BCHUNK / 1024;           // 8 edges per thread
    __shared__ int hist[NBUCKET];                // pass A: counts; pass B: local cursors
    __shared__ int base[NBUCKET];                // global run base for this block
    int t = threadIdx.x;
    int e0 = blockIdx.x * BCHUNK;
    int lim = N_EDGES - e0;

    hist[t] = 0;
    __syncthreads();

    int ds[REG], ss[REG];
#pragma unroll
    for (int i = 0; i < REG; ++i) {
        int idx = t + i * 1024;
        if (idx < lim) {
            ds[i] = dst[e0 + idx];
            ss[i] = src[e0 + idx];
            atomicAdd(&hist[ds[i] >> 7], 1);
        }
    }
    __syncthreads();

    int h = hist[t];
    base[t] = h ? atomicAdd(&bcur[t], h) : 0;    // block-level reservation
    hist[t] = 0;                                 // reuse as local cursor
    __syncthreads();

#pragma unroll
    for (int i = 0; i < REG; ++i) {
        int idx = t + i * 1024;
        if (idx < lim) {
            int b = ds[i] >> 7;
            int pos = base[b] + atomicAdd(&hist[b], 1);
            binned[pos] = ((uint)ss[i] << 7) | (uint)(ds[i] & 127);
        }
    }
}

// ---- pass 2: one block per bucket. LDS count + scan -> row_start, dis, placed csr_src. ----
__global__ __launch_bounds__(256) void csr_from_bins(const uint* __restrict__ binned,
                                                     const int* __restrict__ bbase,
                                                     const int* __restrict__ bcnt,
                                                     int* __restrict__ row_start,
                                                     float* __restrict__ dis,
                                                     int* __restrict__ csr_src) {
    __shared__ int cnt[128];
    __shared__ int ex[128];
    int t = threadIdx.x;
    int b = blockIdx.x;
    if (t < 128) cnt[t] = 0;
    __syncthreads();
    int start = bbase[b];
    int end = start + bcnt[b];
    for (int i = start + t; i < end; i += 256)
        atomicAdd(&cnt[binned[i] & 127u], 1);
    __syncthreads();
    if (t < 128) ex[t] = cnt[t];
    __syncthreads();
    for (int off = 1; off < 128; off <<= 1) {
        int v = (t < 128 && t >= off) ? ex[t - off] : 0;
        __syncthreads();
        if (t < 128) ex[t] += v;
        __syncthreads();
    }
    if (t < 128) {
        int c = cnt[t];
        ex[t] -= c;                              // exclusive
        int node = b * 128 + t;
        if (node < N_NODES) {
            row_start[node] = start + ex[t];
            dis[node] = rsqrtf((float)(c + 1));  // +1 self-loop
        }
        cnt[t] = 0;                              // reuse as cursor
    }
    if (b == 0 && t == 0) row_start[N_NODES] = N_EDGES;
    __syncthreads();
    for (int i = start + t; i < end; i += 256) {
        uint p = binned[i];
        int s = (int)(p >> 7);
        int d = (int)(p & 127u);
        int pos = start + ex[d] + atomicAdd(&cnt[d], 1);
        csr_src[pos] = s;
    }
}

// ---------------- W^T in f16 ----------------
__global__ __launch_bounds__(256) void prep_w(const float* __restrict__ W1,
                                              const float* __restrict__ W2,
                                              f16* __restrict__ wT) {
    int tid = blockIdx.x * 256 + threadIdx.x;
    if (tid < 16384) {                    // W1^T: wT[n*128+k] = W1[k*128+n]
        int n = tid >> 7, k = tid & 127;
        wT[tid] = (f16)W1[k * 128 + n];
    } else if (tid < 24576) {             // W2^T
        int t = tid - 16384;
        int n = t >> 7, k = t & 127;
        wT[tid] = (f16)W2[k * 64 + n];
    }
}

// ---------------- MFMA GEMM layer 1: A = f32 x, scaled by dis, converted while staging ----
__global__ __launch_bounds__(256) void gemm_mfma1(const float* __restrict__ X,
                                                  const float* __restrict__ dis,
                                                  const f16* __restrict__ Bt,
                                                  ushort* __restrict__ Y) {
    constexpr int NT = 8;                 // OUTF = 128
    constexpr int PITCH = 136;
    __shared__ f16 sA[64 * PITCH];
    __shared__ f16 sB[128 * PITCH];
    int tid = threadIdx.x;
    int n0 = blockIdx.x * 64;

    for (int i = tid; i < 64 * 16; i += 256) {
        int r = i >> 4, c = i & 15;
        int n = n0 + r;
        uint4 pk = make_uint4(0, 0, 0, 0);
        if (n < N_NODES) {
            const float4* px = (const float4*)(X + (size_t)n * 128);
            float4 u = px[c * 2], v = px[c * 2 + 1];
            float d = dis[n];
            pk.x = packf16(u.x * d, u.y * d);
            pk.y = packf16(u.z * d, u.w * d);
            pk.z = packf16(v.x * d, v.y * d);
            pk.w = packf16(v.z * d, v.w * d);
        }
        *(uint4*)&sA[r * PITCH + c * 8] = pk;
    }
    for (int i = tid; i < 128 * 16; i += 256) {
        int r = i >> 4, c = i & 15;
        *(uint4*)&sB[r * PITCH + c * 8] = ((const uint4*)(Bt + r * 128))[c];
    }
    __syncthreads();

    int lane = tid & 63, wave = tid >> 6;
    int l15 = lane & 15, q = lane >> 4;
    int m0 = wave * 16;
    f32x4 acc[NT];
#pragma unroll
    for (int nt = 0; nt < NT; ++nt) acc[nt] = (f32x4){0.f, 0.f, 0.f, 0.f};

    const f16* pa = &sA[(m0 + l15) * PITCH + q * 8];
    const f16* pb = &sB[l15 * PITCH + q * 8];
#pragma unroll
    for (int kk = 0; kk < 4; ++kk) {
        f16x8 a = *(const f16x8*)(pa + kk * 32);
#pragma unroll
        for (int nt = 0; nt < NT; ++nt) {
            f16x8 b = *(const f16x8*)(pb + nt * 16 * PITCH + kk * 32);
            acc[nt] = __builtin_amdgcn_mfma_f32_16x16x32_f16(a, b, acc[nt], 0, 0, 0);
        }
    }

    int row_base = n0 + m0 + q * 4;                     // C/D: col=lane&15, row=q*4+reg
#pragma unroll
    for (int nt = 0; nt < NT; ++nt) {
#pragma unroll
        for (int r = 0; r < 4; ++r) {
            int row = row_base + r;
            if (row < N_NODES) {
                union { f16 h; ushort u; } z;
                z.h = (f16)acc[nt][r];
                Y[(size_t)row * 128 + nt * 16 + l15] = z.u;
            }
        }
    }
}

// ---------------- MFMA GEMM (f16 A, K=128): layer 2 ----------------
template <int OUTF>
__global__ __launch_bounds__(256) void gemm_mfma(const f16* __restrict__ A,
                                                 const f16* __restrict__ Bt,
                                                 ushort* __restrict__ Y) {
    constexpr int NT = OUTF / 16;
    constexpr int PITCH = 136;
    __shared__ f16 sA[64 * PITCH];
    __shared__ f16 sB[OUTF * PITCH];
    int tid = threadIdx.x;
    int n0 = blockIdx.x * 64;

    for (int i = tid; i < 64 * 16; i += 256) {
        int r = i >> 4, c = i & 15;
        int n = n0 + r;
        uint4 v = make_uint4(0, 0, 0, 0);
        if (n < N_NODES) v = ((const uint4*)(A + (size_t)n * 128))[c];
        *(uint4*)&sA[r * PITCH + c * 8] = v;
    }
    for (int i = tid; i < OUTF * 16; i += 256) {
        int r = i >> 4, c = i & 15;
        *(uint4*)&sB[r * PITCH + c * 8] = ((const uint4*)(Bt + r * 128))[c];
    }
    __syncthreads();

    int lane = tid & 63, wave = tid >> 6;
    int l15 = lane & 15, q = lane >> 4;
    int m0 = wave * 16;
    f32x4 acc[NT];
#pragma unroll
    for (int nt = 0; nt < NT; ++nt) acc[nt] = (f32x4){0.f, 0.f, 0.f, 0.f};

    const f16* pa = &sA[(m0 + l15) * PITCH + q * 8];
    const f16* pb = &sB[l15 * PITCH + q * 8];
#pragma unroll
    for (int kk = 0; kk < 4; ++kk) {
        f16x8 a = *(const f16x8*)(pa + kk * 32);
#pragma unroll
        for (int nt = 0; nt < NT; ++nt) {
            f16x8 b = *(const f16x8*)(pb + nt * 16 * PITCH + kk * 32);
            acc[nt] = __builtin_amdgcn_mfma_f32_16x16x32_f16(a, b, acc[nt], 0, 0, 0);
        }
    }

    int row_base = n0 + m0 + q * 4;
#pragma unroll
    for (int nt = 0; nt < NT; ++nt) {
#pragma unroll
        for (int r = 0; r < 4; ++r) {
            int row = row_base + r;
            if (row < N_NODES) {
                union { f16 h; ushort u; } z;
                z.h = (f16)acc[nt][r];
                Y[(size_t)row * OUTF + nt * 16 + l15] = z.u;
            }
        }
    }
}

// ---- aggregation L1: full-wave 256B row gathers, 16 edges in flight ----
__global__ __launch_bounds__(256) void aggregate1(const ushort* __restrict__ M,
                                                  const int* __restrict__ row_start,
                                                  const int* __restrict__ csr_src,
                                                  const float* __restrict__ dis,
                                                  const float* __restrict__ bias,
                                                  ushort* __restrict__ H1s) {
    int wv = __builtin_amdgcn_readfirstlane((int)(threadIdx.x >> 6));
    int n = blockIdx.x * 4 + wv;
    if (n >= N_NODES) return;
    int lane = threadIdx.x & 63;
    float dn = dis[n];
    int e0 = row_start[n], e1 = row_start[n + 1];
    const uint* rows = (const uint*)M;                  // 64 uints (=128 f16) per row
    float2 t0 = unpackf16(rows[(size_t)n * 64 + lane]); // self-loop term
    float a0 = t0.x, a1 = t0.y, b0 = 0.f, b1v = 0.f;
    int e = e0;
    for (; e + 16 <= e1; e += 16) {
        int s[16];
#pragma unroll
        for (int j = 0; j < 16; ++j) s[j] = csr_src[e + j];
        uint v[16];
#pragma unroll
        for (int j = 0; j < 16; ++j) v[j] = rows[(size_t)s[j] * 64 + lane];
#pragma unroll
        for (int j = 0; j < 16; ++j) {
            float2 f = unpackf16(v[j]);
            if (j & 1) { b0 += f.x; b1v += f.y; } else { a0 += f.x; a1 += f.y; }
        }
    }
    for (; e + 8 <= e1; e += 8) {
        int s[8];
#pragma unroll
        for (int j = 0; j < 8; ++j) s[j] = csr_src[e + j];
        uint v[8];
#pragma unroll
        for (int j = 0; j < 8; ++j) v[j] = rows[(size_t)s[j] * 64 + lane];
#pragma unroll
        for (int j = 0; j < 8; ++j) {
            float2 f = unpackf16(v[j]);
            if (j & 1) { b0 += f.x; b1v += f.y; } else { a0 += f.x; a1 += f.y; }
        }
    }
    for (; e + 4 <= e1; e += 4) {
        int s0 = csr_src[e], s1 = csr_src[e + 1], s2 = csr_src[e + 2], s3 = csr_src[e + 3];
        uint v0 = rows[(size_t)s0 * 64 + lane];
        uint v1 = rows[(size_t)s1 * 64 + lane];
        uint v2 = rows[(size_t)s2 * 64 + lane];
        uint v3 = rows[(size_t)s3 * 64 + lane];
        float2 f0 = unpackf16(v0), f1 = unpackf16(v1), f2 = unpackf16(v2), f3 = unpackf16(v3);
        a0 += f0.x + f1.x; a1 += f0.y + f1.y;
        b0 += f2.x + f3.x; b1v += f2.y + f3.y;
    }
    for (; e < e1; ++e) {
        float2 f = unpackf16(rows[(size_t)csr_src[e] * 64 + lane]);
        a0 += f.x; a1 += f.y;
    }
    a0 += b0; a1 += b1v;
    a0 = fmaxf(fmaf(a0, dn, bias[2 * lane]), 0.f) * dn;
    a1 = fmaxf(fmaf(a1, dn, bias[2 * lane + 1]), 0.f) * dn;
    ((uint*)H1s)[(size_t)n * 64 + lane] = packf16(a0, a1);
}

// ---- aggregation L2: full-wave 128B row gathers (ushort/lane), 16 edges in flight ----
__global__ __launch_bounds__(256) void aggregate2(const ushort* __restrict__ M,
                                                  const int* __restrict__ row_start,
                                                  const int* __restrict__ csr_src,
                                                  const float* __restrict__ dis,
                                                  const float* __restrict__ bias,
                                                  float* __restrict__ out) {
    int wv = __builtin_amdgcn_readfirstlane((int)(threadIdx.x >> 6));
    int n = blockIdx.x * 4 + wv;
    if (n >= N_NODES) return;
    int lane = threadIdx.x & 63;
    float dn = dis[n];
    int e0 = row_start[n], e1 = row_start[n + 1];
    const f16* rows = (const f16*)M;
    float a0 = (float)rows[(size_t)n * 64 + lane];      // self-loop term
    float a1 = 0.f;
    int e = e0;
    for (; e + 16 <= e1; e += 16) {
        int s[16];
#pragma unroll
        for (int j = 0; j < 16; ++j) s[j] = csr_src[e + j];
        f16 v[16];
#pragma unroll
        for (int j = 0; j < 16; ++j) v[j] = rows[(size_t)s[j] * 64 + lane];
#pragma unroll
        for (int j = 0; j < 16; ++j) {
            if (j & 1) a1 += (float)v[j]; else a0 += (float)v[j];
        }
    }
    for (; e + 8 <= e1; e += 8) {
        int s[8];
#pragma unroll
        for (int j = 0; j < 8; ++j) s[j] = csr_src[e + j];
        f16 v[8];
#pragma unroll
        for (int j = 0; j < 8; ++j) v[j] = rows[(size_t)s[j] * 64 + lane];
#pragma unroll
        for (int j = 0; j < 8; ++j) {
            if (j & 1) a1 += (float)v[j]; else a0 += (float)v[j];
        }
    }
    for (; e + 4 <= e1; e += 4) {
        int s0 = csr_src[e], s1 = csr_src[e + 1], s2 = csr_src[e + 2], s3 = csr_src[e + 3];
        float v0 = (float)rows[(size_t)s0 * 64 + lane];
        float v1 = (float)rows[(size_t)s1 * 64 + lane];
        float v2 = (float)rows[(size_t)s2 * 64 + lane];
        float v3 = (float)rows[(size_t)s3 * 64 + lane];
        a0 += v0 + v1; a1 += v2 + v3;
    }
    for (; e < e1; ++e) a0 += (float)rows[(size_t)csr_src[e] * 64 + lane];
    a0 += a1;
    a0 = fmaf(a0, dn, bias[lane]);
    out[(size_t)n * 64 + lane] = fmaxf(a0, 0.f);
}

// ---------------- pooling ----------------
__global__ __launch_bounds__(64) void pool_graphs(const float* __restrict__ H,
                                                  const int* __restrict__ batch,
                                                  float* __restrict__ pooled) {
    int g = blockIdx.x;
    int lane = threadIdx.x;
    int lo = 0, hi = N_NODES;
    while (lo < hi) { int mid = (lo + hi) >> 1; if (batch[mid] < g) lo = mid + 1; else hi = mid; }
    int start = lo;
    hi = N_NODES;
    while (lo < hi) { int mid = (lo + hi) >> 1; if (batch[mid] < g + 1) lo = mid + 1; else hi = mid; }
    int end = lo;
    float a0 = 0.f, a1 = 0.f;
    int i = start;
    for (; i + 4 <= end; i += 4) {
        a0 += H[(size_t)i * 64 + lane] + H[(size_t)(i + 1) * 64 + lane];
        a1 += H[(size_t)(i + 2) * 64 + lane] + H[(size_t)(i + 3) * 64 + lane];
    }
    for (; i < end; ++i) a0 += H[(size_t)i * 64 + lane];
    pooled[g * 64 + lane] = a0 + a1;
}

// ---------------- BN batch stats -> scale/shift ----------------
__global__ __launch_bounds__(64) void bn_stats(const float* __restrict__ pooled,
                                               const float* __restrict__ gamma,
                                               const float* __restrict__ beta,
                                               float* __restrict__ scale,
                                               float* __restrict__ shift) {
    int f = threadIdx.x;
    float s = 0.f, s2 = 0.f;
    for (int g = 0; g < N_GRAPHS; ++g) {
        float v = pooled[g * 64 + f];
        s += v;
        s2 = fmaf(v, v, s2);
    }
    float mean = s * (1.0f / N_GRAPHS);
    float var = s2 * (1.0f / N_GRAPHS) - mean * mean;
    float istd = rsqrtf(var + BN_EPS);
    float sc = gamma[f] * istd;
    scale[f] = sc;
    shift[f] = beta[f] - mean * sc;
}

// ---------------- head ----------------
__global__ __launch_bounds__(256) void head(const float* __restrict__ pooled,
                                            const float* __restrict__ scale,
                                            const float* __restrict__ shift,
                                            const float* __restrict__ Wo1,
                                            const float* __restrict__ bo1,
                                            const float* __restrict__ Wo2,
                                            const float* __restrict__ bo2,
                                            float* __restrict__ out) {
    __shared__ float sW1[64 * 24];
    __shared__ float sW2[24];
    __shared__ float sb1[24];
    __shared__ float ssc[64];
    __shared__ float ssh[64];
    int tid = threadIdx.x;
    for (int i = tid; i < 64 * 24; i += 256) sW1[i] = Wo1[i];
    if (tid < 24) { sW2[tid] = Wo2[tid]; sb1[tid] = bo1[tid]; }
    if (tid < 64) { ssc[tid] = scale[tid]; ssh[tid] = shift[tid]; }
    __syncthreads();
    int g = blockIdx.x * 256 + tid;
    if (g >= N_GRAPHS) return;
    float xn[64];
    const float* pr = pooled + g * 64;
#pragma unroll
    for (int j = 0; j < 64; ++j) xn[j] = fmaf(pr[j], ssc[j], ssh[j]);
    float o = bo2[0];
#pragma unroll 4
    for (int k = 0; k < 24; ++k) {
        float h = sb1[k];
#pragma unroll
        for (int j = 0; j < 64; ++j) h = fmaf(xn[j], sW1[j * 24 + k], h);
        o = fmaf(fmaxf(h, 0.f), sW2[k], o);
    }
    out[g] = o;
}

extern "C" void kernel_launch(void* const* d_in, const int* in_sizes, int n_in,
                              void* d_out, int out_size, void* d_ws, size_t ws_size,
                              hipStream_t stream) {
    const float* x     = (const float*)d_in[0];
    const int*   ei    = (const int*)d_in[1];   // [2,E]: first E = src, next E = dst
    const int*   batch = (const int*)d_in[2];
    const float* W1    = (const float*)d_in[3];
    const float* b1    = (const float*)d_in[4];
    const float* W2    = (const float*)d_in[5];
    const float* b2    = (const float*)d_in[6];
    const float* gamma = (const float*)d_in[7];
    const float* beta  = (const float*)d_in[8];
    const float* Wo1   = (const float*)d_in[9];
    const float* bo1   = (const float*)d_in[10];
    const float* Wo2   = (const float*)d_in[11];
    const float* bo2   = (const float*)d_in[12];
    float* out = (float*)d_out;               // [512] out, then [512*64] h(=pooled)
    char* ws = (char*)d_ws;

    const int* srcv = ei;
    const int* dstv = ei + N_EDGES;
    int*    bcnt     = (int*)(ws + OFF_BCNT);
    int*    bcur     = (int*)(ws + OFF_BCUR);
    int*    bbase    = (int*)(ws + OFF_BBASE);
    float*  dis      = (float*)(ws + OFF_DIS);
    int*    row_start= (int*)(ws + OFF_ROW);
    float*  scale    = (float*)(ws + OFF_SC);
    float*  shift    = (float*)(ws + OFF_SH);
    f16*    wT       = (f16*)(ws + OFF_WT);
    int*    csr_src  = (int*)(ws + OFF_CSR);
    f16*    bufP     = (f16*)(ws + OFF_P);    // h1s(f16) -> h2(f32)
    ushort* bufQ     = (ushort*)(ws + OFF_Q); // binned(uint, early) -> M1 -> M2
    uint*   binned   = (uint*)(ws + OFF_Q);
    float*  pooled   = out + N_GRAPHS;        // h output region, also used downstream

    hipMemsetAsync(ws + OFF_BCNT, 0, 4096, stream);

    bucket_hist<<<256, 256, 0, stream>>>(dstv, bcnt);
    scan_buckets<<<1, NBUCKET, 0, stream>>>(bcnt, bcur, bbase);
    bin_scatter<<<NCHUNKS, 1024, 0, stream>>>(srcv, dstv, bcur, binned);
    csr_from_bins<<<NBUCKET_USED, 256, 0, stream>>>(binned, bbase, bcnt, row_start, dis, csr_src);

    prep_w<<<96, 256, 0, stream>>>(W1, W2, wT);

    int gblocks = (N_NODES + 63) / 64;
    int ablocks = (N_NODES + 3) / 4;
    gemm_mfma1<<<gblocks, 256, 0, stream>>>(x, dis, wT, bufQ);
    aggregate1<<<ablocks, 256, 0, stream>>>(bufQ, row_start, csr_src, dis, b1, (ushort*)bufP);
    gemm_mfma<64><<<gblocks, 256, 0, stream>>>(bufP, wT + 16384, bufQ);
    aggregate2<<<ablocks, 256, 0, stream>>>(bufQ, row_start, csr_src, dis, b2, (float*)bufP);

    pool_graphs<<<N_GRAPHS, 64, 0, stream>>>((float*)bufP, batch, pooled);
    bn_stats<<<1, 64, 0, stream>>>(pooled, gamma, beta, scale, shift);
    head<<<2, 256, 0, stream>>>(pooled, scale, shift, Wo1, bo1, Wo2, bo2, out);
}

// Round 10
// 329.831 us; speedup vs baseline: 2.5233x; 1.0186x over previous
//
#include <hip/hip_runtime.h>
#include <math.h>

#define N_NODES 100000
#define N_EDGES 1600000
#define N_GRAPHS 512
#define BN_EPS 1e-5f

#define NBUCKET 1024                            // dst>>7 -> 782 used
#define NBUCKET_USED ((N_NODES + 127) / 128)    // 782
#define BCHUNK 8192                             // edges per bin_scatter block
#define NCHUNKS ((N_EDGES + BCHUNK - 1) / BCHUNK)  // 196

typedef unsigned int uint;
typedef unsigned short ushort;
typedef _Float16 f16;
typedef _Float16 f16x8 __attribute__((ext_vector_type(8)));
typedef float f32x4 __attribute__((ext_vector_type(4)));

// ---------------- workspace layout (bytes) ----------------
constexpr size_t OFF_BCNT  = 0;          // int[1024] bucket counts        (memset)
constexpr size_t OFF_BCUR  = 4096;       // int[1024] bucket cursors
constexpr size_t OFF_BBASE = 8192;       // int[1024] bucket exclusive bases
constexpr size_t OFF_DIS   = 12288;      // float[N] rsqrt(deg+1)
constexpr size_t OFF_ROW   = 412288;     // int[N+1] CSR row starts
constexpr size_t OFF_WT    = 812928;     // f16[128*128 + 64*128] W1^T,W2^T
constexpr size_t OFF_CSR   = 862080;     // int[E] CSR src indices
constexpr size_t OFF_P     = 7262080;    // 25.6MB region: M2(f16, 12.8MB)
constexpr size_t OFF_Q     = 32862080;   // 25.6MB region: binned(uint) -> M1(f16) -> h2(f32)

__device__ __forceinline__ uint packf16(float a, float b) {
    union { f16 h[2]; uint u; } z;
    z.h[0] = (f16)a; z.h[1] = (f16)b;
    return z.u;
}
__device__ __forceinline__ float2 unpackf16(uint u) {
    union { uint u; f16 h[2]; } z;
    z.u = u;
    return make_float2((float)z.h[0], (float)z.h[1]);
}

// ---------------- bucket histogram (LDS only) ----------------
__global__ __launch_bounds__(256) void bucket_hist(const int* __restrict__ dst,
                                                   int* __restrict__ bcnt) {
    __shared__ int h[NBUCKET];
    for (int i = threadIdx.x; i < NBUCKET; i += 256) h[i] = 0;
    __syncthreads();
    int stride = gridDim.x * 256;
    for (int e = blockIdx.x * 256 + threadIdx.x; e < N_EDGES; e += stride)
        atomicAdd(&h[dst[e] >> 7], 1);
    __syncthreads();
    for (int i = threadIdx.x; i < NBUCKET; i += 256) {
        int v = h[i];
        if (v) atomicAdd(&bcnt[i], v);
    }
}

// ---------------- bucket scan -> exclusive bases (bcur = working cursor copy) ----------------
__global__ __launch_bounds__(1024) void scan_buckets(const int* __restrict__ bcnt,
                                                     int* __restrict__ bcur,
                                                     int* __restrict__ bbase) {
    __shared__ int tmp[NBUCKET];
    int t = threadIdx.x;
    int c = bcnt[t];
    tmp[t] = c;
    __syncthreads();
    for (int off = 1; off < NBUCKET; off <<= 1) {
        int add = (t >= off) ? tmp[t - off] : 0;
        __syncthreads();
        tmp[t] += add;
        __syncthreads();
    }
    bcur[t] = tmp[t] - c;
    bbase[t] = tmp[t] - c;
}

// ---- pass 1: bin edges by dst>>7. Payload packed in uint: src<<7 | (dst&127). ----
__global__ __launch_bounds__(1024) void bin_scatter(const int* __restrict__ src,
                                                    const int* __restrict__ dst,
                                                    int* __restrict__ bcur,
                                                    uint* __restrict__ binned) {
    constexpr int REG = BCHUNK / 1024;           // 8 edges per thread
    __shared__ int hist[NBUCKET];                // pass A: counts; pass B: local cursors
    __shared__ int base[NBUCKET];                // global run base for this block
    int t = threadIdx.x;
    int e0 = blockIdx.x * BCHUNK;
    int lim = N_EDGES - e0;

    hist[t] = 0;
    __syncthreads();

    int ds[REG], ss[REG];
#pragma unroll
    for (int i = 0; i < REG; ++i) {
        int idx = t + i * 1024;
        if (idx < lim) {
            ds[i] = dst[e0 + idx];
            ss[i] = src[e0 + idx];
            atomicAdd(&hist[ds[i] >> 7], 1);
        }
    }
    __syncthreads();

    int h = hist[t];
    base[t] = h ? atomicAdd(&bcur[t], h) : 0;    // block-level reservation
    hist[t] = 0;                                 // reuse as local cursor
    __syncthreads();

#pragma unroll
    for (int i = 0; i < REG; ++i) {
        int idx = t + i * 1024;
        if (idx < lim) {
            int b = ds[i] >> 7;
            int pos = base[b] + atomicAdd(&hist[b], 1);
            binned[pos] = ((uint)ss[i] << 7) | (uint)(ds[i] & 127);
        }
    }
}

// ---- pass 2: one block per bucket. LDS count + scan -> row_start, dis, placed csr_src. ----
__global__ __launch_bounds__(256) void csr_from_bins(const uint* __restrict__ binned,
                                                     const int* __restrict__ bbase,
                                                     const int* __restrict__ bcnt,
                                                     int* __restrict__ row_start,
                                                     float* __restrict__ dis,
                                                     int* __restrict__ csr_src) {
    __shared__ int cnt[128];
    __shared__ int ex[128];
    int t = threadIdx.x;
    int b = blockIdx.x;
    if (t < 128) cnt[t] = 0;
    __syncthreads();
    int start = bbase[b];
    int end = start + bcnt[b];
    for (int i = start + t; i < end; i += 256)
        atomicAdd(&cnt[binned[i] & 127u], 1);
    __syncthreads();
    if (t < 128) ex[t] = cnt[t];
    __syncthreads();
    for (int off = 1; off < 128; off <<= 1) {
        int v = (t < 128 && t >= off) ? ex[t - off] : 0;
        __syncthreads();
        if (t < 128) ex[t] += v;
        __syncthreads();
    }
    if (t < 128) {
        int c = cnt[t];
        ex[t] -= c;                              // exclusive
        int node = b * 128 + t;
        if (node < N_NODES) {
            row_start[node] = start + ex[t];
            dis[node] = rsqrtf((float)(c + 1));  // +1 self-loop
        }
        cnt[t] = 0;                              // reuse as cursor
    }
    if (b == 0 && t == 0) row_start[N_NODES] = N_EDGES;
    __syncthreads();
    for (int i = start + t; i < end; i += 256) {
        uint p = binned[i];
        int s = (int)(p >> 7);
        int d = (int)(p & 127u);
        int pos = start + ex[d] + atomicAdd(&cnt[d], 1);
        csr_src[pos] = s;
    }
}

// ---------------- W^T in f16 ----------------
__global__ __launch_bounds__(256) void prep_w(const float* __restrict__ W1,
                                              const float* __restrict__ W2,
                                              f16* __restrict__ wT) {
    int tid = blockIdx.x * 256 + threadIdx.x;
    if (tid < 16384) {                    // W1^T: wT[n*128+k] = W1[k*128+n]
        int n = tid >> 7, k = tid & 127;
        wT[tid] = (f16)W1[k * 128 + n];
    } else if (tid < 24576) {             // W2^T
        int t = tid - 16384;
        int n = t >> 7, k = t & 127;
        wT[tid] = (f16)W2[k * 64 + n];
    }
}

// ---------------- MFMA GEMM layer 1: A = f32 x, scaled by dis, converted while staging ----
__global__ __launch_bounds__(256) void gemm_mfma1(const float* __restrict__ X,
                                                  const float* __restrict__ dis,
                                                  const f16* __restrict__ Bt,
                                                  ushort* __restrict__ Y) {
    constexpr int NT = 8;                 // OUTF = 128
    constexpr int PITCH = 136;
    __shared__ f16 sA[64 * PITCH];
    __shared__ f16 sB[128 * PITCH];
    int tid = threadIdx.x;
    int n0 = blockIdx.x * 64;

    for (int i = tid; i < 64 * 16; i += 256) {
        int r = i >> 4, c = i & 15;
        int n = n0 + r;
        uint4 pk = make_uint4(0, 0, 0, 0);
        if (n < N_NODES) {
            const float4* px = (const float4*)(X + (size_t)n * 128);
            float4 u = px[c * 2], v = px[c * 2 + 1];
            float d = dis[n];
            pk.x = packf16(u.x * d, u.y * d);
            pk.y = packf16(u.z * d, u.w * d);
            pk.z = packf16(v.x * d, v.y * d);
            pk.w = packf16(v.z * d, v.w * d);
        }
        *(uint4*)&sA[r * PITCH + c * 8] = pk;
    }
    for (int i = tid; i < 128 * 16; i += 256) {
        int r = i >> 4, c = i & 15;
        *(uint4*)&sB[r * PITCH + c * 8] = ((const uint4*)(Bt + r * 128))[c];
    }
    __syncthreads();

    int lane = tid & 63, wave = tid >> 6;
    int l15 = lane & 15, q = lane >> 4;
    int m0 = wave * 16;
    f32x4 acc[NT];
#pragma unroll
    for (int nt = 0; nt < NT; ++nt) acc[nt] = (f32x4){0.f, 0.f, 0.f, 0.f};

    const f16* pa = &sA[(m0 + l15) * PITCH + q * 8];
    const f16* pb = &sB[l15 * PITCH + q * 8];
#pragma unroll
    for (int kk = 0; kk < 4; ++kk) {
        f16x8 a = *(const f16x8*)(pa + kk * 32);
#pragma unroll
        for (int nt = 0; nt < NT; ++nt) {
            f16x8 b = *(const f16x8*)(pb + nt * 16 * PITCH + kk * 32);
            acc[nt] = __builtin_amdgcn_mfma_f32_16x16x32_f16(a, b, acc[nt], 0, 0, 0);
        }
    }

    int row_base = n0 + m0 + q * 4;                     // C/D: col=lane&15, row=q*4+reg
#pragma unroll
    for (int nt = 0; nt < NT; ++nt) {
#pragma unroll
        for (int r = 0; r < 4; ++r) {
            int row = row_base + r;
            if (row < N_NODES) {
                union { f16 h; ushort u; } z;
                z.h = (f16)acc[nt][r];
                Y[(size_t)row * 128 + nt * 16 + l15] = z.u;
            }
        }
    }
}

// ---- aggregation L1 FUSED with GEMM2: block = 4 waves = 16 nodes.
// ---- Each wave aggregates 4 nodes (full-wave 256B gathers, 16 in flight),
// ---- writes h1s rows to LDS, then block does 16x64 MFMA vs W2^T -> M2 f16.
__global__ __launch_bounds__(256) void aggregate1_fused(const ushort* __restrict__ M,
                                                        const int* __restrict__ row_start,
                                                        const int* __restrict__ csr_src,
                                                        const float* __restrict__ dis,
                                                        const float* __restrict__ bias,
                                                        const f16* __restrict__ W2t,
                                                        ushort* __restrict__ M2) {
    constexpr int PITCH = 136;            // sB pitch in f16
    constexpr int HP = 130;               // sH pitch in f16 (65 uints)
    __shared__ f16 sB[64 * PITCH];
    __shared__ f16 sH[16 * HP];
    int tid = threadIdx.x;
    // stage W2^T [64 out][128 k]
    for (int i = tid; i < 64 * 16; i += 256) {
        int r = i >> 4, c = i & 15;
        *(uint4*)&sB[r * PITCH + c * 8] = ((const uint4*)(W2t + r * 128))[c];
    }
    int wv = __builtin_amdgcn_readfirstlane((int)(tid >> 6));
    int lane = tid & 63;
    int n0 = blockIdx.x * 16;             // 100000 = 6250 * 16 exactly
    const uint* rows = (const uint*)M;    // 64 uints (=128 f16) per row

    for (int i = 0; i < 4; ++i) {
        int r = wv * 4 + i;
        int n = n0 + r;
        float dn = dis[n];
        int e0 = row_start[n], e1 = row_start[n + 1];
        float2 t0 = unpackf16(rows[(size_t)n * 64 + lane]);  // self-loop
        float a0 = t0.x, a1 = t0.y, b0 = 0.f, b1v = 0.f;
        int e = e0;
        for (; e + 16 <= e1; e += 16) {
            int s[16];
#pragma unroll
            for (int j = 0; j < 16; ++j) s[j] = csr_src[e + j];
            uint v[16];
#pragma unroll
            for (int j = 0; j < 16; ++j) v[j] = rows[(size_t)s[j] * 64 + lane];
#pragma unroll
            for (int j = 0; j < 16; ++j) {
                float2 f = unpackf16(v[j]);
                if (j & 1) { b0 += f.x; b1v += f.y; } else { a0 += f.x; a1 += f.y; }
            }
        }
        for (; e + 8 <= e1; e += 8) {
            int s[8];
#pragma unroll
            for (int j = 0; j < 8; ++j) s[j] = csr_src[e + j];
            uint v[8];
#pragma unroll
            for (int j = 0; j < 8; ++j) v[j] = rows[(size_t)s[j] * 64 + lane];
#pragma unroll
            for (int j = 0; j < 8; ++j) {
                float2 f = unpackf16(v[j]);
                if (j & 1) { b0 += f.x; b1v += f.y; } else { a0 += f.x; a1 += f.y; }
            }
        }
        for (; e + 4 <= e1; e += 4) {
            int s0 = csr_src[e], s1 = csr_src[e + 1], s2 = csr_src[e + 2], s3 = csr_src[e + 3];
            uint v0 = rows[(size_t)s0 * 64 + lane];
            uint v1 = rows[(size_t)s1 * 64 + lane];
            uint v2 = rows[(size_t)s2 * 64 + lane];
            uint v3 = rows[(size_t)s3 * 64 + lane];
            float2 f0 = unpackf16(v0), f1 = unpackf16(v1), f2 = unpackf16(v2), f3 = unpackf16(v3);
            a0 += f0.x + f1.x; a1 += f0.y + f1.y;
            b0 += f2.x + f3.x; b1v += f2.y + f3.y;
        }
        for (; e < e1; ++e) {
            float2 f = unpackf16(rows[(size_t)csr_src[e] * 64 + lane]);
            a0 += f.x; a1 += f.y;
        }
        a0 += b0; a1 += b1v;
        a0 = fmaxf(fmaf(a0, dn, bias[2 * lane]), 0.f) * dn;
        a1 = fmaxf(fmaf(a1, dn, bias[2 * lane + 1]), 0.f) * dn;
        *(uint*)&sH[r * HP + 2 * lane] = packf16(a0, a1);   // h1s row r in LDS
    }
    __syncthreads();

    // MFMA: C[16 nodes][64 out] ; wave wv covers out cols wv*16..wv*16+15
    int l15 = lane & 15, q = lane >> 4;
    f32x4 acc = (f32x4){0.f, 0.f, 0.f, 0.f};
    const f16* pa = &sH[l15 * HP + q * 8];
    const f16* pb = &sB[(wv * 16 + l15) * PITCH + q * 8];
#pragma unroll
    for (int kk = 0; kk < 4; ++kk) {
        f16x8 a = *(const f16x8*)(pa + kk * 32);
        f16x8 b = *(const f16x8*)(pb + kk * 32);
        acc = __builtin_amdgcn_mfma_f32_16x16x32_f16(a, b, acc, 0, 0, 0);
    }
    int row_base = n0 + q * 4;                    // C/D: col=lane&15, row=q*4+reg
#pragma unroll
    for (int rr = 0; rr < 4; ++rr) {
        union { f16 h; ushort u; } z;
        z.h = (f16)acc[rr];
        M2[(size_t)(row_base + rr) * 64 + wv * 16 + l15] = z.u;
    }
}

// ---- aggregation L2: full-wave 128B row gathers (ushort/lane), 16 edges in flight ----
__global__ __launch_bounds__(256) void aggregate2(const ushort* __restrict__ M,
                                                  const int* __restrict__ row_start,
                                                  const int* __restrict__ csr_src,
                                                  const float* __restrict__ dis,
                                                  const float* __restrict__ bias,
                                                  float* __restrict__ out) {
    int wv = __builtin_amdgcn_readfirstlane((int)(threadIdx.x >> 6));
    int n = blockIdx.x * 4 + wv;
    if (n >= N_NODES) return;
    int lane = threadIdx.x & 63;
    float dn = dis[n];
    int e0 = row_start[n], e1 = row_start[n + 1];
    const f16* rows = (const f16*)M;
    float a0 = (float)rows[(size_t)n * 64 + lane];      // self-loop term
    float a1 = 0.f;
    int e = e0;
    for (; e + 16 <= e1; e += 16) {
        int s[16];
#pragma unroll
        for (int j = 0; j < 16; ++j) s[j] = csr_src[e + j];
        f16 v[16];
#pragma unroll
        for (int j = 0; j < 16; ++j) v[j] = rows[(size_t)s[j] * 64 + lane];
#pragma unroll
        for (int j = 0; j < 16; ++j) {
            if (j & 1) a1 += (float)v[j]; else a0 += (float)v[j];
        }
    }
    for (; e + 8 <= e1; e += 8) {
        int s[8];
#pragma unroll
        for (int j = 0; j < 8; ++j) s[j] = csr_src[e + j];
        f16 v[8];
#pragma unroll
        for (int j = 0; j < 8; ++j) v[j] = rows[(size_t)s[j] * 64 + lane];
#pragma unroll
        for (int j = 0; j < 8; ++j) {
            if (j & 1) a1 += (float)v[j]; else a0 += (float)v[j];
        }
    }
    for (; e + 4 <= e1; e += 4) {
        int s0 = csr_src[e], s1 = csr_src[e + 1], s2 = csr_src[e + 2], s3 = csr_src[e + 3];
        float v0 = (float)rows[(size_t)s0 * 64 + lane];
        float v1 = (float)rows[(size_t)s1 * 64 + lane];
        float v2 = (float)rows[(size_t)s2 * 64 + lane];
        float v3 = (float)rows[(size_t)s3 * 64 + lane];
        a0 += v0 + v1; a1 += v2 + v3;
    }
    for (; e < e1; ++e) a0 += (float)rows[(size_t)csr_src[e] * 64 + lane];
    a0 += a1;
    a0 = fmaf(a0, dn, bias[lane]);
    out[(size_t)n * 64 + lane] = fmaxf(a0, 0.f);
}

// ---------------- pooling ----------------
__global__ __launch_bounds__(64) void pool_graphs(const float* __restrict__ H,
                                                  const int* __restrict__ batch,
                                                  float* __restrict__ pooled) {
    int g = blockIdx.x;
    int lane = threadIdx.x;
    int lo = 0, hi = N_NODES;
    while (lo < hi) { int mid = (lo + hi) >> 1; if (batch[mid] < g) lo = mid + 1; else hi = mid; }
    int start = lo;
    hi = N_NODES;
    while (lo < hi) { int mid = (lo + hi) >> 1; if (batch[mid] < g + 1) lo = mid + 1; else hi = mid; }
    int end = lo;
    float a0 = 0.f, a1 = 0.f;
    int i = start;
    for (; i + 4 <= end; i += 4) {
        a0 += H[(size_t)i * 64 + lane] + H[(size_t)(i + 1) * 64 + lane];
        a1 += H[(size_t)(i + 2) * 64 + lane] + H[(size_t)(i + 3) * 64 + lane];
    }
    for (; i < end; ++i) a0 += H[(size_t)i * 64 + lane];
    pooled[g * 64 + lane] = a0 + a1;
}

// ---------------- BN stats + head fused (single block, 512 threads) ----------------
__global__ __launch_bounds__(512) void bn_head(const float* __restrict__ pooled,
                                               const float* __restrict__ gamma,
                                               const float* __restrict__ beta,
                                               const float* __restrict__ Wo1,
                                               const float* __restrict__ bo1,
                                               const float* __restrict__ Wo2,
                                               const float* __restrict__ bo2,
                                               float* __restrict__ out) {
    __shared__ float sW1[64 * 24];
    __shared__ float sW2[24];
    __shared__ float sb1[24];
    __shared__ float ssc[64];
    __shared__ float ssh[64];
    int tid = threadIdx.x;
    for (int i = tid; i < 64 * 24; i += 512) sW1[i] = Wo1[i];
    if (tid >= 64 && tid < 88) { int k = tid - 64; sW2[k] = Wo2[k]; sb1[k] = bo1[k]; }
    if (tid < 64) {
        float s = 0.f, s2 = 0.f;
        for (int g = 0; g < N_GRAPHS; ++g) {
            float v = pooled[g * 64 + tid];
            s += v;
            s2 = fmaf(v, v, s2);
        }
        float mean = s * (1.0f / N_GRAPHS);
        float var = s2 * (1.0f / N_GRAPHS) - mean * mean;
        float istd = rsqrtf(var + BN_EPS);
        float sc = gamma[tid] * istd;
        ssc[tid] = sc;
        ssh[tid] = beta[tid] - mean * sc;
    }
    __syncthreads();
    int g = tid;                                  // 512 graphs = 512 threads
    float xn[64];
    const float* pr = pooled + g * 64;
#pragma unroll
    for (int j = 0; j < 64; ++j) xn[j] = fmaf(pr[j], ssc[j], ssh[j]);
    float o = bo2[0];
#pragma unroll 4
    for (int k = 0; k < 24; ++k) {
        float h = sb1[k];
#pragma unroll
        for (int j = 0; j < 64; ++j) h = fmaf(xn[j], sW1[j * 24 + k], h);
        o = fmaf(fmaxf(h, 0.f), sW2[k], o);
    }
    out[g] = o;
}

extern "C" void kernel_launch(void* const* d_in, const int* in_sizes, int n_in,
                              void* d_out, int out_size, void* d_ws, size_t ws_size,
                              hipStream_t stream) {
    const float* x     = (const float*)d_in[0];
    const int*   ei    = (const int*)d_in[1];   // [2,E]: first E = src, next E = dst
    const int*   batch = (const int*)d_in[2];
    const float* W1    = (const float*)d_in[3];
    const float* b1    = (const float*)d_in[4];
    const float* W2    = (const float*)d_in[5];
    const float* b2    = (const float*)d_in[6];
    const float* gamma = (const float*)d_in[7];
    const float* beta  = (const float*)d_in[8];
    const float* Wo1   = (const float*)d_in[9];
    const float* bo1   = (const float*)d_in[10];
    const float* Wo2   = (const float*)d_in[11];
    const float* bo2   = (const float*)d_in[12];
    float* out = (float*)d_out;               // [512] out, then [512*64] h(=pooled)
    char* ws = (char*)d_ws;

    const int* srcv = ei;
    const int* dstv = ei + N_EDGES;
    int*    bcnt     = (int*)(ws + OFF_BCNT);
    int*    bcur     = (int*)(ws + OFF_BCUR);
    int*    bbase    = (int*)(ws + OFF_BBASE);
    float*  dis      = (float*)(ws + OFF_DIS);
    int*    row_start= (int*)(ws + OFF_ROW);
    f16*    wT       = (f16*)(ws + OFF_WT);
    int*    csr_src  = (int*)(ws + OFF_CSR);
    ushort* bufP     = (ushort*)(ws + OFF_P); // M2 (f16)
    ushort* bufQ     = (ushort*)(ws + OFF_Q); // binned(uint) -> M1(f16) -> h2(f32)
    uint*   binned   = (uint*)(ws + OFF_Q);
    float*  pooled   = out + N_GRAPHS;        // h output region, also used downstream

    hipMemsetAsync(ws + OFF_BCNT, 0, 4096, stream);

    bucket_hist<<<256, 256, 0, stream>>>(dstv, bcnt);
    scan_buckets<<<1, NBUCKET, 0, stream>>>(bcnt, bcur, bbase);
    bin_scatter<<<NCHUNKS, 1024, 0, stream>>>(srcv, dstv, bcur, binned);
    csr_from_bins<<<NBUCKET_USED, 256, 0, stream>>>(binned, bbase, bcnt, row_start, dis, csr_src);

    prep_w<<<96, 256, 0, stream>>>(W1, W2, wT);

    int gblocks = (N_NODES + 63) / 64;
    gemm_mfma1<<<gblocks, 256, 0, stream>>>(x, dis, wT, bufQ);
    aggregate1_fused<<<N_NODES / 16, 256, 0, stream>>>(bufQ, row_start, csr_src, dis, b1,
                                                       wT + 16384, bufP);
    aggregate2<<<(N_NODES + 3) / 4, 256, 0, stream>>>(bufP, row_start, csr_src, dis, b2,
                                                      (float*)bufQ);

    pool_graphs<<<N_GRAPHS, 64, 0, stream>>>((float*)bufQ, batch, pooled);
    bn_head<<<1, 512, 0, stream>>>(pooled, gamma, beta, Wo1, bo1, Wo2, bo2, out);
}

// Round 11
// 307.866 us; speedup vs baseline: 2.7033x; 1.0713x over previous
//
#include <hip/hip_runtime.h>
#include <math.h>

#define N_NODES 100000
#define N_EDGES 1600000
#define N_GRAPHS 512
#define BN_EPS 1e-5f

#define NBUCKET 1024                            // dst>>7 -> 782 used
#define NBUCKET_USED ((N_NODES + 127) / 128)    // 782
#define BCHUNK 8192                             // edges per bin_scatter block
#define NCHUNKS ((N_EDGES + BCHUNK - 1) / BCHUNK)  // 196

typedef unsigned int uint;
typedef unsigned short ushort;
typedef unsigned char uchar;
typedef _Float16 f16;
typedef _Float16 f16x8 __attribute__((ext_vector_type(8)));
typedef float f32x4 __attribute__((ext_vector_type(4)));
typedef float f32x2 __attribute__((ext_vector_type(2)));

// ---------------- workspace layout (bytes) ----------------
constexpr size_t OFF_BCNT  = 0;          // int[1024] bucket counts        (memset)
constexpr size_t OFF_BCUR  = 4096;       // int[1024] bucket cursors
constexpr size_t OFF_BBASE = 8192;       // int[1024] bucket exclusive bases
constexpr size_t OFF_DIS   = 12288;      // float[N] rsqrt(deg+1)
constexpr size_t OFF_ROW   = 412288;     // int[N+1] CSR row starts
constexpr size_t OFF_WT    = 812928;     // f16[128*128 + 64*128] W1^T,W2^T
constexpr size_t OFF_CSR   = 862080;     // int[E] CSR src indices
constexpr size_t OFF_P     = 7262080;    // M2 fp8 [N*64] = 6.4MB
constexpr size_t OFF_Q     = 32862080;   // 25.6MB region: binned(uint) -> M1 fp8 [N*128] -> h2(f32)

__device__ __forceinline__ uint packf16(float a, float b) {
    union { f16 h[2]; uint u; } z;
    z.h[0] = (f16)a; z.h[1] = (f16)b;
    return z.u;
}
__device__ __forceinline__ float2 unpackf16(uint u) {
    union { uint u; f16 h[2]; } z;
    z.u = u;
    return make_float2((float)z.h[0], (float)z.h[1]);
}
__device__ __forceinline__ uchar f2fp8(float v) {
    return (uchar)(__builtin_amdgcn_cvt_pk_fp8_f32(v, v, 0, false) & 0xff);
}

// ---------------- bucket histogram (LDS only) ----------------
__global__ __launch_bounds__(256) void bucket_hist(const int* __restrict__ dst,
                                                   int* __restrict__ bcnt) {
    __shared__ int h[NBUCKET];
    for (int i = threadIdx.x; i < NBUCKET; i += 256) h[i] = 0;
    __syncthreads();
    int stride = gridDim.x * 256;
    for (int e = blockIdx.x * 256 + threadIdx.x; e < N_EDGES; e += stride)
        atomicAdd(&h[dst[e] >> 7], 1);
    __syncthreads();
    for (int i = threadIdx.x; i < NBUCKET; i += 256) {
        int v = h[i];
        if (v) atomicAdd(&bcnt[i], v);
    }
}

// ---------------- bucket scan -> exclusive bases (bcur = working cursor copy) ----------------
__global__ __launch_bounds__(1024) void scan_buckets(const int* __restrict__ bcnt,
                                                     int* __restrict__ bcur,
                                                     int* __restrict__ bbase) {
    __shared__ int tmp[NBUCKET];
    int t = threadIdx.x;
    int c = bcnt[t];
    tmp[t] = c;
    __syncthreads();
    for (int off = 1; off < NBUCKET; off <<= 1) {
        int add = (t >= off) ? tmp[t - off] : 0;
        __syncthreads();
        tmp[t] += add;
        __syncthreads();
    }
    bcur[t] = tmp[t] - c;
    bbase[t] = tmp[t] - c;
}

// ---- pass 1: bin edges by dst>>7. Payload packed in uint: src<<7 | (dst&127). ----
__global__ __launch_bounds__(1024) void bin_scatter(const int* __restrict__ src,
                                                    const int* __restrict__ dst,
                                                    int* __restrict__ bcur,
                                                    uint* __restrict__ binned) {
    constexpr int REG = BCHUNK / 1024;           // 8 edges per thread
    __shared__ int hist[NBUCKET];                // pass A: counts; pass B: local cursors
    __shared__ int base[NBUCKET];                // global run base for this block
    int t = threadIdx.x;
    int e0 = blockIdx.x * BCHUNK;
    int lim = N_EDGES - e0;

    hist[t] = 0;
    __syncthreads();

    int ds[REG], ss[REG];
#pragma unroll
    for (int i = 0; i < REG; ++i) {
        int idx = t + i * 1024;
        if (idx < lim) {
            ds[i] = dst[e0 + idx];
            ss[i] = src[e0 + idx];
            atomicAdd(&hist[ds[i] >> 7], 1);
        }
    }
    __syncthreads();

    int h = hist[t];
    base[t] = h ? atomicAdd(&bcur[t], h) : 0;    // block-level reservation
    hist[t] = 0;                                 // reuse as local cursor
    __syncthreads();

#pragma unroll
    for (int i = 0; i < REG; ++i) {
        int idx = t + i * 1024;
        if (idx < lim) {
            int b = ds[i] >> 7;
            int pos = base[b] + atomicAdd(&hist[b], 1);
            binned[pos] = ((uint)ss[i] << 7) | (uint)(ds[i] & 127);
        }
    }
}

// ---- pass 2: one block per bucket. LDS count + scan -> row_start, dis, placed csr_src. ----
__global__ __launch_bounds__(256) void csr_from_bins(const uint* __restrict__ binned,
                                                     const int* __restrict__ bbase,
                                                     const int* __restrict__ bcnt,
                                                     int* __restrict__ row_start,
                                                     float* __restrict__ dis,
                                                     int* __restrict__ csr_src) {
    __shared__ int cnt[128];
    __shared__ int ex[128];
    int t = threadIdx.x;
    int b = blockIdx.x;
    if (t < 128) cnt[t] = 0;
    __syncthreads();
    int start = bbase[b];
    int end = start + bcnt[b];
    for (int i = start + t; i < end; i += 256)
        atomicAdd(&cnt[binned[i] & 127u], 1);
    __syncthreads();
    if (t < 128) ex[t] = cnt[t];
    __syncthreads();
    for (int off = 1; off < 128; off <<= 1) {
        int v = (t < 128 && t >= off) ? ex[t - off] : 0;
        __syncthreads();
        if (t < 128) ex[t] += v;
        __syncthreads();
    }
    if (t < 128) {
        int c = cnt[t];
        ex[t] -= c;                              // exclusive
        int node = b * 128 + t;
        if (node < N_NODES) {
            row_start[node] = start + ex[t];
            dis[node] = rsqrtf((float)(c + 1));  // +1 self-loop
        }
        cnt[t] = 0;                              // reuse as cursor
    }
    if (b == 0 && t == 0) row_start[N_NODES] = N_EDGES;
    __syncthreads();
    for (int i = start + t; i < end; i += 256) {
        uint p = binned[i];
        int s = (int)(p >> 7);
        int d = (int)(p & 127u);
        int pos = start + ex[d] + atomicAdd(&cnt[d], 1);
        csr_src[pos] = s;
    }
}

// ---------------- W^T in f16 ----------------
__global__ __launch_bounds__(256) void prep_w(const float* __restrict__ W1,
                                              const float* __restrict__ W2,
                                              f16* __restrict__ wT) {
    int tid = blockIdx.x * 256 + threadIdx.x;
    if (tid < 16384) {                    // W1^T: wT[n*128+k] = W1[k*128+n]
        int n = tid >> 7, k = tid & 127;
        wT[tid] = (f16)W1[k * 128 + n];
    } else if (tid < 24576) {             // W2^T
        int t = tid - 16384;
        int n = t >> 7, k = t & 127;
        wT[tid] = (f16)W2[k * 64 + n];
    }
}

// ---------------- MFMA GEMM layer 1: A = f32 x, scaled by dis; output M1 = fp8 ----------------
__global__ __launch_bounds__(256) void gemm_mfma1(const float* __restrict__ X,
                                                  const float* __restrict__ dis,
                                                  const f16* __restrict__ Bt,
                                                  uchar* __restrict__ Y) {
    constexpr int NT = 8;                 // OUTF = 128
    constexpr int PITCH = 136;
    __shared__ f16 sA[64 * PITCH];
    __shared__ f16 sB[128 * PITCH];
    int tid = threadIdx.x;
    int n0 = blockIdx.x * 64;

    for (int i = tid; i < 64 * 16; i += 256) {
        int r = i >> 4, c = i & 15;
        int n = n0 + r;
        uint4 pk = make_uint4(0, 0, 0, 0);
        if (n < N_NODES) {
            const float4* px = (const float4*)(X + (size_t)n * 128);
            float4 u = px[c * 2], v = px[c * 2 + 1];
            float d = dis[n];
            pk.x = packf16(u.x * d, u.y * d);
            pk.y = packf16(u.z * d, u.w * d);
            pk.z = packf16(v.x * d, v.y * d);
            pk.w = packf16(v.z * d, v.w * d);
        }
        *(uint4*)&sA[r * PITCH + c * 8] = pk;
    }
    for (int i = tid; i < 128 * 16; i += 256) {
        int r = i >> 4, c = i & 15;
        *(uint4*)&sB[r * PITCH + c * 8] = ((const uint4*)(Bt + r * 128))[c];
    }
    __syncthreads();

    int lane = tid & 63, wave = tid >> 6;
    int l15 = lane & 15, q = lane >> 4;
    int m0 = wave * 16;
    f32x4 acc[NT];
#pragma unroll
    for (int nt = 0; nt < NT; ++nt) acc[nt] = (f32x4){0.f, 0.f, 0.f, 0.f};

    const f16* pa = &sA[(m0 + l15) * PITCH + q * 8];
    const f16* pb = &sB[l15 * PITCH + q * 8];
#pragma unroll
    for (int kk = 0; kk < 4; ++kk) {
        f16x8 a = *(const f16x8*)(pa + kk * 32);
#pragma unroll
        for (int nt = 0; nt < NT; ++nt) {
            f16x8 b = *(const f16x8*)(pb + nt * 16 * PITCH + kk * 32);
            acc[nt] = __builtin_amdgcn_mfma_f32_16x16x32_f16(a, b, acc[nt], 0, 0, 0);
        }
    }

    int row_base = n0 + m0 + q * 4;                     // C/D: col=lane&15, row=q*4+reg
#pragma unroll
    for (int nt = 0; nt < NT; ++nt) {
#pragma unroll
        for (int r = 0; r < 4; ++r) {
            int row = row_base + r;
            if (row < N_NODES)
                Y[(size_t)row * 128 + nt * 16 + l15] = f2fp8(acc[nt][r]);
        }
    }
}

// ---- aggregation L1 FUSED with GEMM2. M1 fp8 rows (128B). Each wave aggregates
// ---- 4 nodes (full-wave 128B gathers, 16 in flight), h1s -> LDS f16, then
// ---- 16x64 MFMA vs W2^T -> M2 fp8.
__global__ __launch_bounds__(256) void aggregate1_fused(const ushort* __restrict__ M,
                                                        const int* __restrict__ row_start,
                                                        const int* __restrict__ csr_src,
                                                        const float* __restrict__ dis,
                                                        const float* __restrict__ bias,
                                                        const f16* __restrict__ W2t,
                                                        uchar* __restrict__ M2) {
    constexpr int PITCH = 136;            // sB pitch in f16
    constexpr int HP = 130;               // sH pitch in f16 (65 uints)
    __shared__ f16 sB[64 * PITCH];
    __shared__ f16 sH[16 * HP];
    int tid = threadIdx.x;
    // stage W2^T [64 out][128 k]
    for (int i = tid; i < 64 * 16; i += 256) {
        int r = i >> 4, c = i & 15;
        *(uint4*)&sB[r * PITCH + c * 8] = ((const uint4*)(W2t + r * 128))[c];
    }
    int wv = __builtin_amdgcn_readfirstlane((int)(tid >> 6));
    int lane = tid & 63;
    int n0 = blockIdx.x * 16;             // 100000 = 6250 * 16 exactly
    // M1: fp8 rows of 128 -> 64 ushorts per row; lane holds features 2*lane, 2*lane+1

    for (int i = 0; i < 4; ++i) {
        int r = wv * 4 + i;
        int n = n0 + r;
        float dn = dis[n];
        int e0 = row_start[n], e1 = row_start[n + 1];
        f32x2 t0 = __builtin_amdgcn_cvt_pk_f32_fp8((int)M[(size_t)n * 64 + lane], false);
        float a0 = t0.x, a1 = t0.y, b0 = 0.f, b1v = 0.f;
        int e = e0;
        for (; e + 16 <= e1; e += 16) {
            int s[16];
#pragma unroll
            for (int j = 0; j < 16; ++j) s[j] = csr_src[e + j];
            ushort v[16];
#pragma unroll
            for (int j = 0; j < 16; ++j) v[j] = M[(size_t)s[j] * 64 + lane];
#pragma unroll
            for (int j = 0; j < 16; ++j) {
                f32x2 f = __builtin_amdgcn_cvt_pk_f32_fp8((int)v[j], false);
                if (j & 1) { b0 += f.x; b1v += f.y; } else { a0 += f.x; a1 += f.y; }
            }
        }
        for (; e + 8 <= e1; e += 8) {
            int s[8];
#pragma unroll
            for (int j = 0; j < 8; ++j) s[j] = csr_src[e + j];
            ushort v[8];
#pragma unroll
            for (int j = 0; j < 8; ++j) v[j] = M[(size_t)s[j] * 64 + lane];
#pragma unroll
            for (int j = 0; j < 8; ++j) {
                f32x2 f = __builtin_amdgcn_cvt_pk_f32_fp8((int)v[j], false);
                if (j & 1) { b0 += f.x; b1v += f.y; } else { a0 += f.x; a1 += f.y; }
            }
        }
        for (; e + 4 <= e1; e += 4) {
            int s0 = csr_src[e], s1 = csr_src[e + 1], s2 = csr_src[e + 2], s3 = csr_src[e + 3];
            ushort v0 = M[(size_t)s0 * 64 + lane];
            ushort v1 = M[(size_t)s1 * 64 + lane];
            ushort v2 = M[(size_t)s2 * 64 + lane];
            ushort v3 = M[(size_t)s3 * 64 + lane];
            f32x2 f0 = __builtin_amdgcn_cvt_pk_f32_fp8((int)v0, false);
            f32x2 f1 = __builtin_amdgcn_cvt_pk_f32_fp8((int)v1, false);
            f32x2 f2 = __builtin_amdgcn_cvt_pk_f32_fp8((int)v2, false);
            f32x2 f3 = __builtin_amdgcn_cvt_pk_f32_fp8((int)v3, false);
            a0 += f0.x + f1.x; a1 += f0.y + f1.y;
            b0 += f2.x + f3.x; b1v += f2.y + f3.y;
        }
        for (; e < e1; ++e) {
            f32x2 f = __builtin_amdgcn_cvt_pk_f32_fp8((int)M[(size_t)csr_src[e] * 64 + lane], false);
            a0 += f.x; a1 += f.y;
        }
        a0 += b0; a1 += b1v;
        a0 = fmaxf(fmaf(a0, dn, bias[2 * lane]), 0.f) * dn;
        a1 = fmaxf(fmaf(a1, dn, bias[2 * lane + 1]), 0.f) * dn;
        *(uint*)&sH[r * HP + 2 * lane] = packf16(a0, a1);   // h1s row r in LDS (f16)
    }
    __syncthreads();

    // MFMA: C[16 nodes][64 out] ; wave wv covers out cols wv*16..wv*16+15
    int l15 = lane & 15, q = lane >> 4;
    f32x4 acc = (f32x4){0.f, 0.f, 0.f, 0.f};
    const f16* pa = &sH[l15 * HP + q * 8];
    const f16* pb = &sB[(wv * 16 + l15) * PITCH + q * 8];
#pragma unroll
    for (int kk = 0; kk < 4; ++kk) {
        f16x8 a = *(const f16x8*)(pa + kk * 32);
        f16x8 b = *(const f16x8*)(pb + kk * 32);
        acc = __builtin_amdgcn_mfma_f32_16x16x32_f16(a, b, acc, 0, 0, 0);
    }
    int row_base = n0 + q * 4;                    // C/D: col=lane&15, row=q*4+reg
#pragma unroll
    for (int rr = 0; rr < 4; ++rr)
        M2[(size_t)(row_base + rr) * 64 + wv * 16 + l15] = f2fp8(acc[rr]);
}

// ---- aggregation L2: M2 fp8 rows = 64B = ONE cache line per edge; 16 in flight ----
__global__ __launch_bounds__(256) void aggregate2(const uchar* __restrict__ M,
                                                  const int* __restrict__ row_start,
                                                  const int* __restrict__ csr_src,
                                                  const float* __restrict__ dis,
                                                  const float* __restrict__ bias,
                                                  float* __restrict__ out) {
    int wv = __builtin_amdgcn_readfirstlane((int)(threadIdx.x >> 6));
    int n = blockIdx.x * 4 + wv;
    if (n >= N_NODES) return;
    int lane = threadIdx.x & 63;
    float dn = dis[n];
    int e0 = row_start[n], e1 = row_start[n + 1];
    float a0 = __builtin_amdgcn_cvt_f32_fp8((int)M[(size_t)n * 64 + lane], 0);  // self-loop
    float a1 = 0.f;
    int e = e0;
    for (; e + 16 <= e1; e += 16) {
        int s[16];
#pragma unroll
        for (int j = 0; j < 16; ++j) s[j] = csr_src[e + j];
        uchar v[16];
#pragma unroll
        for (int j = 0; j < 16; ++j) v[j] = M[(size_t)s[j] * 64 + lane];
#pragma unroll
        for (int j = 0; j < 16; ++j) {
            float f = __builtin_amdgcn_cvt_f32_fp8((int)v[j], 0);
            if (j & 1) a1 += f; else a0 += f;
        }
    }
    for (; e + 8 <= e1; e += 8) {
        int s[8];
#pragma unroll
        for (int j = 0; j < 8; ++j) s[j] = csr_src[e + j];
        uchar v[8];
#pragma unroll
        for (int j = 0; j < 8; ++j) v[j] = M[(size_t)s[j] * 64 + lane];
#pragma unroll
        for (int j = 0; j < 8; ++j) {
            float f = __builtin_amdgcn_cvt_f32_fp8((int)v[j], 0);
            if (j & 1) a1 += f; else a0 += f;
        }
    }
    for (; e + 4 <= e1; e += 4) {
        int s0 = csr_src[e], s1 = csr_src[e + 1], s2 = csr_src[e + 2], s3 = csr_src[e + 3];
        float v0 = __builtin_amdgcn_cvt_f32_fp8((int)M[(size_t)s0 * 64 + lane], 0);
        float v1 = __builtin_amdgcn_cvt_f32_fp8((int)M[(size_t)s1 * 64 + lane], 0);
        float v2 = __builtin_amdgcn_cvt_f32_fp8((int)M[(size_t)s2 * 64 + lane], 0);
        float v3 = __builtin_amdgcn_cvt_f32_fp8((int)M[(size_t)s3 * 64 + lane], 0);
        a0 += v0 + v1; a1 += v2 + v3;
    }
    for (; e < e1; ++e)
        a0 += __builtin_amdgcn_cvt_f32_fp8((int)M[(size_t)csr_src[e] * 64 + lane], 0);
    a0 += a1;
    a0 = fmaf(a0, dn, bias[lane]);
    out[(size_t)n * 64 + lane] = fmaxf(a0, 0.f);
}

// ---------------- pooling ----------------
__global__ __launch_bounds__(64) void pool_graphs(const float* __restrict__ H,
                                                  const int* __restrict__ batch,
                                                  float* __restrict__ pooled) {
    int g = blockIdx.x;
    int lane = threadIdx.x;
    int lo = 0, hi = N_NODES;
    while (lo < hi) { int mid = (lo + hi) >> 1; if (batch[mid] < g) lo = mid + 1; else hi = mid; }
    int start = lo;
    hi = N_NODES;
    while (lo < hi) { int mid = (lo + hi) >> 1; if (batch[mid] < g + 1) lo = mid + 1; else hi = mid; }
    int end = lo;
    float a0 = 0.f, a1 = 0.f;
    int i = start;
    for (; i + 4 <= end; i += 4) {
        a0 += H[(size_t)i * 64 + lane] + H[(size_t)(i + 1) * 64 + lane];
        a1 += H[(size_t)(i + 2) * 64 + lane] + H[(size_t)(i + 3) * 64 + lane];
    }
    for (; i < end; ++i) a0 += H[(size_t)i * 64 + lane];
    pooled[g * 64 + lane] = a0 + a1;
}

// ---------------- BN stats + head fused (single block, 512 threads) ----------------
__global__ __launch_bounds__(512) void bn_head(const float* __restrict__ pooled,
                                               const float* __restrict__ gamma,
                                               const float* __restrict__ beta,
                                               const float* __restrict__ Wo1,
                                               const float* __restrict__ bo1,
                                               const float* __restrict__ Wo2,
                                               const float* __restrict__ bo2,
                                               float* __restrict__ out) {
    __shared__ float sW1[64 * 24];
    __shared__ float sW2[24];
    __shared__ float sb1[24];
    __shared__ float ssc[64];
    __shared__ float ssh[64];
    int tid = threadIdx.x;
    for (int i = tid; i < 64 * 24; i += 512) sW1[i] = Wo1[i];
    if (tid >= 64 && tid < 88) { int k = tid - 64; sW2[k] = Wo2[k]; sb1[k] = bo1[k]; }
    if (tid < 64) {
        float s = 0.f, s2 = 0.f;
        for (int g = 0; g < N_GRAPHS; ++g) {
            float v = pooled[g * 64 + tid];
            s += v;
            s2 = fmaf(v, v, s2);
        }
        float mean = s * (1.0f / N_GRAPHS);
        float var = s2 * (1.0f / N_GRAPHS) - mean * mean;
        float istd = rsqrtf(var + BN_EPS);
        float sc = gamma[tid] * istd;
        ssc[tid] = sc;
        ssh[tid] = beta[tid] - mean * sc;
    }
    __syncthreads();
    int g = tid;                                  // 512 graphs = 512 threads
    float xn[64];
    const float* pr = pooled + g * 64;
#pragma unroll
    for (int j = 0; j < 64; ++j) xn[j] = fmaf(pr[j], ssc[j], ssh[j]);
    float o = bo2[0];
#pragma unroll 4
    for (int k = 0; k < 24; ++k) {
        float h = sb1[k];
#pragma unroll
        for (int j = 0; j < 64; ++j) h = fmaf(xn[j], sW1[j * 24 + k], h);
        o = fmaf(fmaxf(h, 0.f), sW2[k], o);
    }
    out[g] = o;
}

extern "C" void kernel_launch(void* const* d_in, const int* in_sizes, int n_in,
                              void* d_out, int out_size, void* d_ws, size_t ws_size,
                              hipStream_t stream) {
    const float* x     = (const float*)d_in[0];
    const int*   ei    = (const int*)d_in[1];   // [2,E]: first E = src, next E = dst
    const int*   batch = (const int*)d_in[2];
    const float* W1    = (const float*)d_in[3];
    const float* b1    = (const float*)d_in[4];
    const float* W2    = (const float*)d_in[5];
    const float* b2    = (const float*)d_in[6];
    const float* gamma = (const float*)d_in[7];
    const float* beta  = (const float*)d_in[8];
    const float* Wo1   = (const float*)d_in[9];
    const float* bo1   = (const float*)d_in[10];
    const float* Wo2   = (const float*)d_in[11];
    const float* bo2   = (const float*)d_in[12];
    float* out = (float*)d_out;               // [512] out, then [512*64] h(=pooled)
    char* ws = (char*)d_ws;

    const int* srcv = ei;
    const int* dstv = ei + N_EDGES;
    int*    bcnt     = (int*)(ws + OFF_BCNT);
    int*    bcur     = (int*)(ws + OFF_BCUR);
    int*    bbase    = (int*)(ws + OFF_BBASE);
    float*  dis      = (float*)(ws + OFF_DIS);
    int*    row_start= (int*)(ws + OFF_ROW);
    f16*    wT       = (f16*)(ws + OFF_WT);
    int*    csr_src  = (int*)(ws + OFF_CSR);
    uchar*  bufP     = (uchar*)(ws + OFF_P);  // M2 (fp8)
    uchar*  bufQ     = (uchar*)(ws + OFF_Q);  // binned(uint) -> M1(fp8) -> h2(f32)
    uint*   binned   = (uint*)(ws + OFF_Q);
    float*  pooled   = out + N_GRAPHS;        // h output region, also used downstream

    hipMemsetAsync(ws + OFF_BCNT, 0, 4096, stream);

    bucket_hist<<<256, 256, 0, stream>>>(dstv, bcnt);
    scan_buckets<<<1, NBUCKET, 0, stream>>>(bcnt, bcur, bbase);
    bin_scatter<<<NCHUNKS, 1024, 0, stream>>>(srcv, dstv, bcur, binned);
    csr_from_bins<<<NBUCKET_USED, 256, 0, stream>>>(binned, bbase, bcnt, row_start, dis, csr_src);

    prep_w<<<96, 256, 0, stream>>>(W1, W2, wT);

    int gblocks = (N_NODES + 63) / 64;
    gemm_mfma1<<<gblocks, 256, 0, stream>>>(x, dis, wT, bufQ);
    aggregate1_fused<<<N_NODES / 16, 256, 0, stream>>>((const ushort*)bufQ, row_start, csr_src,
                                                       dis, b1, wT + 16384, bufP);
    aggregate2<<<(N_NODES + 3) / 4, 256, 0, stream>>>(bufP, row_start, csr_src, dis, b2,
                                                      (float*)bufQ);

    pool_graphs<<<N_GRAPHS, 64, 0, stream>>>((float*)bufQ, batch, pooled);
    bn_head<<<1, 512, 0, stream>>>(pooled, gamma, beta, Wo1, bo1, Wo2, bo2, out);
}

// Round 12
// 276.545 us; speedup vs baseline: 3.0095x; 1.1133x over previous
//
#include <hip/hip_runtime.h>
#include <math.h>

#define N_NODES 100000
#define N_EDGES 1600000
#define N_GRAPHS 512
#define BN_EPS 1e-5f

#define NBUCKET 1024                            // dst>>7 -> 782 used
#define NBUCKET_USED ((N_NODES + 127) / 128)    // 782
#define SLOT 2560                               // slab capacity per bucket (mean 2048, sd 45)
#define BCHUNK 8192                             // edges per bin_scatter block
#define NCHUNKS ((N_EDGES + BCHUNK - 1) / BCHUNK)  // 196

typedef unsigned int uint;
typedef unsigned short ushort;
typedef unsigned char uchar;
typedef _Float16 f16;
typedef _Float16 f16x8 __attribute__((ext_vector_type(8)));
typedef float f32x4 __attribute__((ext_vector_type(4)));
typedef float f32x2 __attribute__((ext_vector_type(2)));

// ---------------- workspace layout (bytes) ----------------
constexpr size_t OFF_BCUR = 0;          // int[1024] bucket cursors (zeroed by init_prep)
constexpr size_t OFF_DIS  = 4096;       // float[N] rsqrt(deg+1)
constexpr size_t OFF_ROW  = 404096;     // int[N] CSR row starts (slab-absolute)
constexpr size_t OFF_END  = 804096;     // int[N] CSR row ends
constexpr size_t OFF_WT   = 1204096;    // f16[128*128 + 64*128] W1^T,W2^T
constexpr size_t OFF_BIN  = 1253248;    // uint[1024*2560] binned slabs = 10.5MB
constexpr size_t OFF_CSR  = 11739008;   // int[1024*2560] CSR slabs = 10.5MB
constexpr size_t OFF_P    = 22224768;   // M2 fp8 [N*64] = 6.4MB
constexpr size_t OFF_Q    = 28624768;   // M1 fp8 [N*128] = 12.8MB
constexpr size_t OFF_H2   = 41424768;   // h2 f16 [N*64] = 12.8MB

__device__ __forceinline__ uint packf16(float a, float b) {
    union { f16 h[2]; uint u; } z;
    z.h[0] = (f16)a; z.h[1] = (f16)b;
    return z.u;
}
__device__ __forceinline__ uchar f2fp8(float v) {
    return (uchar)(__builtin_amdgcn_cvt_pk_fp8_f32(v, v, 0, false) & 0xff);
}

// ---------------- init: W^T in f16 (blocks 0..95) + zero cursors (block 96) ----------------
__global__ __launch_bounds__(256) void init_prep(const float* __restrict__ W1,
                                                 const float* __restrict__ W2,
                                                 f16* __restrict__ wT,
                                                 int* __restrict__ bcur) {
    int b = blockIdx.x;
    if (b == 96) {
        int t = threadIdx.x;
        bcur[t] = 0; bcur[t + 256] = 0; bcur[t + 512] = 0; bcur[t + 768] = 0;
        return;
    }
    int tid = b * 256 + threadIdx.x;
    if (tid < 16384) {                    // W1^T: wT[n*128+k] = W1[k*128+n]
        int n = tid >> 7, k = tid & 127;
        wT[tid] = (f16)W1[k * 128 + n];
    } else {                              // W2^T
        int t = tid - 16384;
        int n = t >> 7, k = t & 127;
        wT[tid] = (f16)W2[k * 64 + n];
    }
}

// ---- pass 1: bin edges by dst>>7 into fixed slabs. Per-edge atomics in LDS only;
// ---- one global atomicAdd per (block,bucket) reserves a run in the bucket's slab. ----
__global__ __launch_bounds__(1024) void bin_scatter(const int* __restrict__ src,
                                                    const int* __restrict__ dst,
                                                    int* __restrict__ bcur,
                                                    uint* __restrict__ binned) {
    constexpr int REG = BCHUNK / 1024;           // 8 edges per thread
    __shared__ int hist[NBUCKET];                // pass A: counts; pass B: local cursors
    __shared__ int base[NBUCKET];                // slab-local run base for this block
    int t = threadIdx.x;
    int e0 = blockIdx.x * BCHUNK;
    int lim = N_EDGES - e0;

    hist[t] = 0;
    __syncthreads();

    int ds[REG], ss[REG];
#pragma unroll
    for (int i = 0; i < REG; ++i) {
        int idx = t + i * 1024;
        if (idx < lim) {
            ds[i] = dst[e0 + idx];
            ss[i] = src[e0 + idx];
            atomicAdd(&hist[ds[i] >> 7], 1);
        }
    }
    __syncthreads();

    int h = hist[t];
    base[t] = h ? atomicAdd(&bcur[t], h) : 0;    // block-level reservation in slab
    hist[t] = 0;                                 // reuse as local cursor
    __syncthreads();

#pragma unroll
    for (int i = 0; i < REG; ++i) {
        int idx = t + i * 1024;
        if (idx < lim) {
            int b = ds[i] >> 7;
            int pos = b * SLOT + base[b] + atomicAdd(&hist[b], 1);
            binned[pos] = ((uint)ss[i] << 7) | (uint)(ds[i] & 127);
        }
    }
}

// ---- pass 2: one block per bucket. LDS count + scan -> row_start/row_end, dis,
// ---- placed csr_src (slab-organized). Zero global atomics. ----
__global__ __launch_bounds__(256) void csr_from_bins(const uint* __restrict__ binned,
                                                     const int* __restrict__ bcur,
                                                     int* __restrict__ row_start,
                                                     int* __restrict__ row_end,
                                                     float* __restrict__ dis,
                                                     int* __restrict__ csr_src) {
    __shared__ int cnt[128];
    __shared__ int ex[128];
    int t = threadIdx.x;
    int b = blockIdx.x;
    if (t < 128) cnt[t] = 0;
    __syncthreads();
    int base = b * SLOT;
    int nb = bcur[b];                            // edges in this bucket
    for (int i = t; i < nb; i += 256)
        atomicAdd(&cnt[binned[base + i] & 127u], 1);
    __syncthreads();
    if (t < 128) ex[t] = cnt[t];
    __syncthreads();
    for (int off = 1; off < 128; off <<= 1) {
        int v = (t < 128 && t >= off) ? ex[t - off] : 0;
        __syncthreads();
        if (t < 128) ex[t] += v;
        __syncthreads();
    }
    if (t < 128) {
        int c = cnt[t];
        ex[t] -= c;                              // exclusive
        int node = b * 128 + t;
        if (node < N_NODES) {
            int rs = base + ex[t];
            row_start[node] = rs;
            row_end[node] = rs + c;
            dis[node] = rsqrtf((float)(c + 1));  // +1 self-loop
        }
        cnt[t] = 0;                              // reuse as cursor
    }
    __syncthreads();
    for (int i = t; i < nb; i += 256) {
        uint p = binned[base + i];
        int s = (int)(p >> 7);
        int d = (int)(p & 127u);
        int pos = base + ex[d] + atomicAdd(&cnt[d], 1);
        csr_src[pos] = s;
    }
}

// ---------------- MFMA GEMM layer 1: A = f32 x, scaled by dis; output M1 = fp8 ----------------
__global__ __launch_bounds__(256) void gemm_mfma1(const float* __restrict__ X,
                                                  const float* __restrict__ dis,
                                                  const f16* __restrict__ Bt,
                                                  uchar* __restrict__ Y) {
    constexpr int NT = 8;                 // OUTF = 128
    constexpr int PITCH = 136;
    __shared__ f16 sA[64 * PITCH];
    __shared__ f16 sB[128 * PITCH];
    int tid = threadIdx.x;
    int n0 = blockIdx.x * 64;

    for (int i = tid; i < 64 * 16; i += 256) {
        int r = i >> 4, c = i & 15;
        int n = n0 + r;
        uint4 pk = make_uint4(0, 0, 0, 0);
        if (n < N_NODES) {
            const float4* px = (const float4*)(X + (size_t)n * 128);
            float4 u = px[c * 2], v = px[c * 2 + 1];
            float d = dis[n];
            pk.x = packf16(u.x * d, u.y * d);
            pk.y = packf16(u.z * d, u.w * d);
            pk.z = packf16(v.x * d, v.y * d);
            pk.w = packf16(v.z * d, v.w * d);
        }
        *(uint4*)&sA[r * PITCH + c * 8] = pk;
    }
    for (int i = tid; i < 128 * 16; i += 256) {
        int r = i >> 4, c = i & 15;
        *(uint4*)&sB[r * PITCH + c * 8] = ((const uint4*)(Bt + r * 128))[c];
    }
    __syncthreads();

    int lane = tid & 63, wave = tid >> 6;
    int l15 = lane & 15, q = lane >> 4;
    int m0 = wave * 16;
    f32x4 acc[NT];
#pragma unroll
    for (int nt = 0; nt < NT; ++nt) acc[nt] = (f32x4){0.f, 0.f, 0.f, 0.f};

    const f16* pa = &sA[(m0 + l15) * PITCH + q * 8];
    const f16* pb = &sB[l15 * PITCH + q * 8];
#pragma unroll
    for (int kk = 0; kk < 4; ++kk) {
        f16x8 a = *(const f16x8*)(pa + kk * 32);
#pragma unroll
        for (int nt = 0; nt < NT; ++nt) {
            f16x8 b = *(const f16x8*)(pb + nt * 16 * PITCH + kk * 32);
            acc[nt] = __builtin_amdgcn_mfma_f32_16x16x32_f16(a, b, acc[nt], 0, 0, 0);
        }
    }

    int row_base = n0 + m0 + q * 4;                     // C/D: col=lane&15, row=q*4+reg
#pragma unroll
    for (int nt = 0; nt < NT; ++nt) {
#pragma unroll
        for (int r = 0; r < 4; ++r) {
            int row = row_base + r;
            if (row < N_NODES)
                Y[(size_t)row * 128 + nt * 16 + l15] = f2fp8(acc[nt][r]);
        }
    }
}

// ---- aggregation L1 FUSED with GEMM2. M1 fp8 rows (128B). Each wave aggregates
// ---- 4 nodes (full-wave gathers, 16 in flight), h1s -> LDS f16, then
// ---- 16x64 MFMA vs W2^T -> M2 fp8.
__global__ __launch_bounds__(256) void aggregate1_fused(const ushort* __restrict__ M,
                                                        const int* __restrict__ row_start,
                                                        const int* __restrict__ row_end,
                                                        const int* __restrict__ csr_src,
                                                        const float* __restrict__ dis,
                                                        const float* __restrict__ bias,
                                                        const f16* __restrict__ W2t,
                                                        uchar* __restrict__ M2) {
    constexpr int PITCH = 136;            // sB pitch in f16
    constexpr int HP = 130;               // sH pitch in f16 (65 uints)
    __shared__ f16 sB[64 * PITCH];
    __shared__ f16 sH[16 * HP];
    int tid = threadIdx.x;
    // stage W2^T [64 out][128 k]
    for (int i = tid; i < 64 * 16; i += 256) {
        int r = i >> 4, c = i & 15;
        *(uint4*)&sB[r * PITCH + c * 8] = ((const uint4*)(W2t + r * 128))[c];
    }
    int wv = __builtin_amdgcn_readfirstlane((int)(tid >> 6));
    int lane = tid & 63;
    int n0 = blockIdx.x * 16;             // 100000 = 6250 * 16 exactly

    for (int i = 0; i < 4; ++i) {
        int r = wv * 4 + i;
        int n = n0 + r;
        float dn = dis[n];
        int e0 = row_start[n], e1 = row_end[n];
        f32x2 t0 = __builtin_amdgcn_cvt_pk_f32_fp8((int)M[(size_t)n * 64 + lane], false);
        float a0 = t0.x, a1 = t0.y, b0 = 0.f, b1v = 0.f;
        int e = e0;
        for (; e + 16 <= e1; e += 16) {
            int s[16];
#pragma unroll
            for (int j = 0; j < 16; ++j) s[j] = csr_src[e + j];
            ushort v[16];
#pragma unroll
            for (int j = 0; j < 16; ++j) v[j] = M[(size_t)s[j] * 64 + lane];
#pragma unroll
            for (int j = 0; j < 16; ++j) {
                f32x2 f = __builtin_amdgcn_cvt_pk_f32_fp8((int)v[j], false);
                if (j & 1) { b0 += f.x; b1v += f.y; } else { a0 += f.x; a1 += f.y; }
            }
        }
        for (; e + 8 <= e1; e += 8) {
            int s[8];
#pragma unroll
            for (int j = 0; j < 8; ++j) s[j] = csr_src[e + j];
            ushort v[8];
#pragma unroll
            for (int j = 0; j < 8; ++j) v[j] = M[(size_t)s[j] * 64 + lane];
#pragma unroll
            for (int j = 0; j < 8; ++j) {
                f32x2 f = __builtin_amdgcn_cvt_pk_f32_fp8((int)v[j], false);
                if (j & 1) { b0 += f.x; b1v += f.y; } else { a0 += f.x; a1 += f.y; }
            }
        }
        for (; e + 4 <= e1; e += 4) {
            int s0 = csr_src[e], s1 = csr_src[e + 1], s2 = csr_src[e + 2], s3 = csr_src[e + 3];
            ushort v0 = M[(size_t)s0 * 64 + lane];
            ushort v1 = M[(size_t)s1 * 64 + lane];
            ushort v2 = M[(size_t)s2 * 64 + lane];
            ushort v3 = M[(size_t)s3 * 64 + lane];
            f32x2 f0 = __builtin_amdgcn_cvt_pk_f32_fp8((int)v0, false);
            f32x2 f1 = __builtin_amdgcn_cvt_pk_f32_fp8((int)v1, false);
            f32x2 f2 = __builtin_amdgcn_cvt_pk_f32_fp8((int)v2, false);
            f32x2 f3 = __builtin_amdgcn_cvt_pk_f32_fp8((int)v3, false);
            a0 += f0.x + f1.x; a1 += f0.y + f1.y;
            b0 += f2.x + f3.x; b1v += f2.y + f3.y;
        }
        for (; e < e1; ++e) {
            f32x2 f = __builtin_amdgcn_cvt_pk_f32_fp8((int)M[(size_t)csr_src[e] * 64 + lane], false);
            a0 += f.x; a1 += f.y;
        }
        a0 += b0; a1 += b1v;
        a0 = fmaxf(fmaf(a0, dn, bias[2 * lane]), 0.f) * dn;
        a1 = fmaxf(fmaf(a1, dn, bias[2 * lane + 1]), 0.f) * dn;
        *(uint*)&sH[r * HP + 2 * lane] = packf16(a0, a1);   // h1s row r in LDS (f16)
    }
    __syncthreads();

    // MFMA: C[16 nodes][64 out] ; wave wv covers out cols wv*16..wv*16+15
    int l15 = lane & 15, q = lane >> 4;
    f32x4 acc = (f32x4){0.f, 0.f, 0.f, 0.f};
    const f16* pa = &sH[l15 * HP + q * 8];
    const f16* pb = &sB[(wv * 16 + l15) * PITCH + q * 8];
#pragma unroll
    for (int kk = 0; kk < 4; ++kk) {
        f16x8 a = *(const f16x8*)(pa + kk * 32);
        f16x8 b = *(const f16x8*)(pb + kk * 32);
        acc = __builtin_amdgcn_mfma_f32_16x16x32_f16(a, b, acc, 0, 0, 0);
    }
    int row_base = n0 + q * 4;                    // C/D: col=lane&15, row=q*4+reg
#pragma unroll
    for (int rr = 0; rr < 4; ++rr)
        M2[(size_t)(row_base + rr) * 64 + wv * 16 + l15] = f2fp8(acc[rr]);
}

// ---- aggregation L2: M2 fp8 rows = 64B = one cache line per edge; 16 in flight; out f16 ----
__global__ __launch_bounds__(256) void aggregate2(const uchar* __restrict__ M,
                                                  const int* __restrict__ row_start,
                                                  const int* __restrict__ row_end,
                                                  const int* __restrict__ csr_src,
                                                  const float* __restrict__ dis,
                                                  const float* __restrict__ bias,
                                                  ushort* __restrict__ out) {
    int wv = __builtin_amdgcn_readfirstlane((int)(threadIdx.x >> 6));
    int n = blockIdx.x * 4 + wv;
    if (n >= N_NODES) return;
    int lane = threadIdx.x & 63;
    float dn = dis[n];
    int e0 = row_start[n], e1 = row_end[n];
    float a0 = __builtin_amdgcn_cvt_f32_fp8((int)M[(size_t)n * 64 + lane], 0);  // self-loop
    float a1 = 0.f;
    int e = e0;
    for (; e + 16 <= e1; e += 16) {
        int s[16];
#pragma unroll
        for (int j = 0; j < 16; ++j) s[j] = csr_src[e + j];
        uchar v[16];
#pragma unroll
        for (int j = 0; j < 16; ++j) v[j] = M[(size_t)s[j] * 64 + lane];
#pragma unroll
        for (int j = 0; j < 16; ++j) {
            float f = __builtin_amdgcn_cvt_f32_fp8((int)v[j], 0);
            if (j & 1) a1 += f; else a0 += f;
        }
    }
    for (; e + 8 <= e1; e += 8) {
        int s[8];
#pragma unroll
        for (int j = 0; j < 8; ++j) s[j] = csr_src[e + j];
        uchar v[8];
#pragma unroll
        for (int j = 0; j < 8; ++j) v[j] = M[(size_t)s[j] * 64 + lane];
#pragma unroll
        for (int j = 0; j < 8; ++j) {
            float f = __builtin_amdgcn_cvt_f32_fp8((int)v[j], 0);
            if (j & 1) a1 += f; else a0 += f;
        }
    }
    for (; e + 4 <= e1; e += 4) {
        int s0 = csr_src[e], s1 = csr_src[e + 1], s2 = csr_src[e + 2], s3 = csr_src[e + 3];
        float v0 = __builtin_amdgcn_cvt_f32_fp8((int)M[(size_t)s0 * 64 + lane], 0);
        float v1 = __builtin_amdgcn_cvt_f32_fp8((int)M[(size_t)s1 * 64 + lane], 0);
        float v2 = __builtin_amdgcn_cvt_f32_fp8((int)M[(size_t)s2 * 64 + lane], 0);
        float v3 = __builtin_amdgcn_cvt_f32_fp8((int)M[(size_t)s3 * 64 + lane], 0);
        a0 += v0 + v1; a1 += v2 + v3;
    }
    for (; e < e1; ++e)
        a0 += __builtin_amdgcn_cvt_f32_fp8((int)M[(size_t)csr_src[e] * 64 + lane], 0);
    a0 += a1;
    a0 = fmaxf(fmaf(a0, dn, bias[lane]), 0.f);
    union { f16 h; ushort u; } z;
    z.h = (f16)a0;
    out[(size_t)n * 64 + lane] = z.u;
}

// ---------------- pooling: 4 waves per graph, LDS combine ----------------
__global__ __launch_bounds__(256) void pool_graphs(const ushort* __restrict__ H,
                                                   const int* __restrict__ batch,
                                                   float* __restrict__ pooled) {
    __shared__ float part[4][64];
    int g = blockIdx.x;
    int tid = threadIdx.x;
    int wv = tid >> 6, lane = tid & 63;
    int lo = 0, hi = N_NODES;
    while (lo < hi) { int mid = (lo + hi) >> 1; if (batch[mid] < g) lo = mid + 1; else hi = mid; }
    int start = lo;
    hi = N_NODES;
    while (lo < hi) { int mid = (lo + hi) >> 1; if (batch[mid] < g + 1) lo = mid + 1; else hi = mid; }
    int end = lo;
    const f16* rows = (const f16*)H;
    float a0 = 0.f, a1 = 0.f;
    int i = start + wv;
    for (; i + 12 < end; i += 16) {
        a0 += (float)rows[(size_t)i * 64 + lane] + (float)rows[(size_t)(i + 4) * 64 + lane];
        a1 += (float)rows[(size_t)(i + 8) * 64 + lane] + (float)rows[(size_t)(i + 12) * 64 + lane];
    }
    for (; i < end; i += 4) a0 += (float)rows[(size_t)i * 64 + lane];
    part[wv][lane] = a0 + a1;
    __syncthreads();
    if (wv == 0)
        pooled[g * 64 + lane] = part[0][lane] + part[1][lane] + part[2][lane] + part[3][lane];
}

// ---------------- BN stats + head fused (single block, 512 threads) ----------------
__global__ __launch_bounds__(512) void bn_head(const float* __restrict__ pooled,
                                               const float* __restrict__ gamma,
                                               const float* __restrict__ beta,
                                               const float* __restrict__ Wo1,
                                               const float* __restrict__ bo1,
                                               const float* __restrict__ Wo2,
                                               const float* __restrict__ bo2,
                                               float* __restrict__ out) {
    __shared__ float sW1[64 * 24];
    __shared__ float sW2[24];
    __shared__ float sb1[24];
    __shared__ float ssc[64];
    __shared__ float ssh[64];
    int tid = threadIdx.x;
    for (int i = tid; i < 64 * 24; i += 512) sW1[i] = Wo1[i];
    if (tid >= 64 && tid < 88) { int k = tid - 64; sW2[k] = Wo2[k]; sb1[k] = bo1[k]; }
    if (tid < 64) {
        float s = 0.f, s2 = 0.f;
        for (int g = 0; g < N_GRAPHS; ++g) {
            float v = pooled[g * 64 + tid];
            s += v;
            s2 = fmaf(v, v, s2);
        }
        float mean = s * (1.0f / N_GRAPHS);
        float var = s2 * (1.0f / N_GRAPHS) - mean * mean;
        float istd = rsqrtf(var + BN_EPS);
        float sc = gamma[tid] * istd;
        ssc[tid] = sc;
        ssh[tid] = beta[tid] - mean * sc;
    }
    __syncthreads();
    int g = tid;                                  // 512 graphs = 512 threads
    float xn[64];
    const float* pr = pooled + g * 64;
#pragma unroll
    for (int j = 0; j < 64; ++j) xn[j] = fmaf(pr[j], ssc[j], ssh[j]);
    float o = bo2[0];
#pragma unroll 4
    for (int k = 0; k < 24; ++k) {
        float h = sb1[k];
#pragma unroll
        for (int j = 0; j < 64; ++j) h = fmaf(xn[j], sW1[j * 24 + k], h);
        o = fmaf(fmaxf(h, 0.f), sW2[k], o);
    }
    out[g] = o;
}

extern "C" void kernel_launch(void* const* d_in, const int* in_sizes, int n_in,
                              void* d_out, int out_size, void* d_ws, size_t ws_size,
                              hipStream_t stream) {
    const float* x     = (const float*)d_in[0];
    const int*   ei    = (const int*)d_in[1];   // [2,E]: first E = src, next E = dst
    const int*   batch = (const int*)d_in[2];
    const float* W1    = (const float*)d_in[3];
    const float* b1    = (const float*)d_in[4];
    const float* W2    = (const float*)d_in[5];
    const float* b2    = (const float*)d_in[6];
    const float* gamma = (const float*)d_in[7];
    const float* beta  = (const float*)d_in[8];
    const float* Wo1   = (const float*)d_in[9];
    const float* bo1   = (const float*)d_in[10];
    const float* Wo2   = (const float*)d_in[11];
    const float* bo2   = (const float*)d_in[12];
    float* out = (float*)d_out;               // [512] out, then [512*64] h(=pooled)
    char* ws = (char*)d_ws;

    const int* srcv = ei;
    const int* dstv = ei + N_EDGES;
    int*    bcur     = (int*)(ws + OFF_BCUR);
    float*  dis      = (float*)(ws + OFF_DIS);
    int*    row_start= (int*)(ws + OFF_ROW);
    int*    row_end  = (int*)(ws + OFF_END);
    f16*    wT       = (f16*)(ws + OFF_WT);
    uint*   binned   = (uint*)(ws + OFF_BIN);
    int*    csr_src  = (int*)(ws + OFF_CSR);
    uchar*  bufP     = (uchar*)(ws + OFF_P);  // M2 (fp8)
    uchar*  bufQ     = (uchar*)(ws + OFF_Q);  // M1 (fp8)
    ushort* h2       = (ushort*)(ws + OFF_H2);// h2 (f16)
    float*  pooled   = out + N_GRAPHS;        // h output region, also used downstream

    init_prep<<<97, 256, 0, stream>>>(W1, W2, wT, bcur);
    bin_scatter<<<NCHUNKS, 1024, 0, stream>>>(srcv, dstv, bcur, binned);
    csr_from_bins<<<NBUCKET_USED, 256, 0, stream>>>(binned, bcur, row_start, row_end, dis, csr_src);

    int gblocks = (N_NODES + 63) / 64;
    gemm_mfma1<<<gblocks, 256, 0, stream>>>(x, dis, wT, bufQ);
    aggregate1_fused<<<N_NODES / 16, 256, 0, stream>>>((const ushort*)bufQ, row_start, row_end,
                                                       csr_src, dis, b1, wT + 16384, bufP);
    aggregate2<<<(N_NODES + 3) / 4, 256, 0, stream>>>(bufP, row_start, row_end, csr_src, dis, b2,
                                                      h2);

    pool_graphs<<<N_GRAPHS, 256, 0, stream>>>(h2, batch, pooled);
    bn_head<<<1, 512, 0, stream>>>(pooled, gamma, beta, Wo1, bo1, Wo2, bo2, out);
}